// Round 1
// 448.886 us; speedup vs baseline: 1.1370x; 1.1370x over previous
//
#include <hip/hip_runtime.h>
#include <hip/hip_bf16.h>
#include <cstdint>

#define E_DIM   1280
#define NHEADS  20
#define HDIM    64
#define QKV_LD  3840   // 3*E

typedef __attribute__((ext_vector_type(8))) short bf8_t;   // 8 bf16 (4 VGPRs)
typedef __attribute__((ext_vector_type(4))) short bf4_t;   // 4 bf16 (2 VGPRs)
typedef __attribute__((ext_vector_type(4))) float f4_t;    // MFMA accumulator

__device__ __forceinline__ short f2bs(float f) {
    union { __hip_bfloat16 h; short s; } u;
    u.h = __float2bfloat16(f);
    return u.s;
}

__device__ __forceinline__ f4_t mfma16x32(bf8_t a, bf8_t b, f4_t c) {
    return __builtin_amdgcn_mfma_f32_16x16x32_bf16(a, b, c, 0, 0, 0);
}
__device__ __forceinline__ f4_t mfma16x16(bf4_t a, bf4_t b, f4_t c) {
    return __builtin_amdgcn_mfma_f32_16x16x16bf16_1k(a, b, c, 0, 0, 0);
}

// async global->LDS, 16B per lane. LDS dest is wave-uniform base + lane*16.
__device__ __forceinline__ void gl_lds16(const void* g, void* l) {
    auto gp = reinterpret_cast<__attribute__((address_space(1))) unsigned int*>(
        reinterpret_cast<uintptr_t>(g));
    auto lp = reinterpret_cast<__attribute__((address_space(3))) unsigned int*>(
        reinterpret_cast<uintptr_t>(l));
    __builtin_amdgcn_global_load_lds(gp, lp, 16, 0, 0);
}

// ---------------- prep: casts + weight concat + bias concat ----------------
// Wq/bq scale = d^-0.5 * log2(e): softmax computed in base-2 domain (exp2f).
#define QSCALE 0.18033688011112042f

__device__ __forceinline__ void cvt8(__hip_bfloat16* dst, const float* src, float sc) {
    float4 a = *(const float4*)src;
    float4 b = *(const float4*)(src + 4);
    bf8_t v;
    v[0] = f2bs(a.x * sc); v[1] = f2bs(a.y * sc); v[2] = f2bs(a.z * sc); v[3] = f2bs(a.w * sc);
    v[4] = f2bs(b.x * sc); v[5] = f2bs(b.y * sc); v[6] = f2bs(b.z * sc); v[7] = f2bs(b.w * sc);
    *(bf8_t*)dst = v;
}

__global__ __launch_bounds__(256) void prep_kernel(
    const float* __restrict__ x,
    const float* __restrict__ wq, const float* __restrict__ wk,
    const float* __restrict__ wv, const float* __restrict__ wo,
    const float* __restrict__ bq, const float* __restrict__ bk, const float* __restrict__ bv,
    __hip_bfloat16* __restrict__ xbf, __hip_bfloat16* __restrict__ wqkv,
    __hip_bfloat16* __restrict__ wobf, float* __restrict__ bqkv,
    long nx8, long nw8, long nb8)
{
    long u = (long)blockIdx.x * 256 + threadIdx.x;
    if (u < nx8) { cvt8(xbf + u * 8, x + u * 8, 1.0f); return; }
    u -= nx8;
    if (u < 3 * nw8) {
        long e = u * 8;
        long w1 = nw8 * 8;
        const float* src; float sc;
        if (e < w1)            { src = wq + e;           sc = QSCALE; }
        else if (e < 2 * w1)   { src = wk + (e - w1);    sc = 1.0f; }
        else                   { src = wv + (e - 2*w1);  sc = 1.0f; }
        cvt8(wqkv + e, src, sc);
        return;
    }
    u -= 3 * nw8;
    if (u < nw8) { cvt8(wobf + u * 8, wo + u * 8, 1.0f); return; }
    u -= nw8;
    if (u < nb8) {
        long e = u * 8;
        #pragma unroll
        for (int j = 0; j < 8; j++) {
            long i = e + j;
            float v;
            if (i < E_DIM)           v = bq[i] * QSCALE;
            else if (i < 2 * E_DIM)  v = bk[i - E_DIM];
            else                     v = bv[i - 2 * E_DIM];
            bqkv[i] = v;
        }
    }
}

// ---------------- m97-style NT GEMM: C = A(MxK) * B(NxK)^T + bias ----------------
template<bool BF16_OUT>
__global__ __launch_bounds__(256, 3) void gemm_nt(
    const __hip_bfloat16* __restrict__ A, const __hip_bfloat16* __restrict__ Bw,
    const float* __restrict__ bias, void* __restrict__ Cout,
    int M, int N, int K, int ldc)
{
    __shared__ __align__(16) __hip_bfloat16 As[128 * 32];
    __shared__ __align__(16) __hip_bfloat16 Bs[128 * 32];
    const int t = threadIdx.x;
    const int wv = t >> 6;
    const int ln = t & 63;
    const int m16 = ln & 15, q4 = ln >> 4;
    const int row0 = blockIdx.y * 128, col0 = blockIdx.x * 128;
    const int wm = (wv >> 1) * 64, wn = (wv & 1) * 64;

    f4_t acc[4][4] = {};

    for (int k0 = 0; k0 < K; k0 += 32) {
        #pragma unroll
        for (int i = 0; i < 2; i++) {
            int s = i * 256 + t;
            int r = s >> 2, c = s & 3;
            gl_lds16(A + (size_t)(row0 + r) * K + k0 + c * 8,
                     As + (size_t)(i * 256 + wv * 64) * 8);
        }
        #pragma unroll
        for (int i = 0; i < 2; i++) {
            int s = i * 256 + t;
            int r = s >> 2, c = s & 3;
            gl_lds16(Bw + (size_t)(col0 + r) * K + k0 + c * 8,
                     Bs + (size_t)(i * 256 + wv * 64) * 8);
        }
        __syncthreads();
        bf8_t af[4], bfr[4];
        #pragma unroll
        for (int mt = 0; mt < 4; mt++)
            af[mt] = *(const bf8_t*)&As[(wm + mt * 16 + m16) * 32 + q4 * 8];
        #pragma unroll
        for (int nt = 0; nt < 4; nt++)
            bfr[nt] = *(const bf8_t*)&Bs[(wn + nt * 16 + m16) * 32 + q4 * 8];
        #pragma unroll
        for (int mt = 0; mt < 4; mt++)
            #pragma unroll
            for (int nt = 0; nt < 4; nt++)
                acc[mt][nt] = mfma16x32(af[mt], bfr[nt], acc[mt][nt]);
        __syncthreads();
    }

    #pragma unroll
    for (int nt = 0; nt < 4; nt++) {
        int cg = col0 + wn + nt * 16 + m16;
        float bv = bias[cg];
        #pragma unroll
        for (int mt = 0; mt < 4; mt++) {
            #pragma unroll
            for (int r = 0; r < 4; r++) {
                int rg = row0 + wm + mt * 16 + q4 * 4 + r;
                float v = acc[mt][nt][r] + bv;
                if constexpr (BF16_OUT)
                    ((__hip_bfloat16*)Cout)[(long)rg * ldc + cg] = __float2bfloat16(v);
                else
                    ((float*)Cout)[(long)rg * ldc + cg] = v;
            }
        }
    }
}

// ---------------- RoPE (in place on q,k sections of qkv) ----------------
__global__ __launch_bounds__(256) void rope_kernel(
    __hip_bfloat16* __restrict__ qkv, const int* __restrict__ cu, int B, int T)
{
    long idx = (long)blockIdx.x * 256 + threadIdx.x;
    int i = idx & 31;
    long r = idx >> 5;
    int h = (int)(r % NHEADS);
    int tok = (int)(r / NHEADS);
    if (tok >= T) return;
    int pos = tok;
    for (int b = 1; b <= B; b++) if (tok >= cu[b]) pos = tok - cu[b];
    float f = (float)pos * exp2f(-(float)i * 0.41524100558003436f);
    float s, c;
    sincosf(f, &s, &c);
    long base = (long)tok * QKV_LD + h * HDIM + i;
    {
        float q1 = __bfloat162float(qkv[base]);
        float q2 = __bfloat162float(qkv[base + 32]);
        qkv[base]      = __float2bfloat16(q1 * c - q2 * s);
        qkv[base + 32] = __float2bfloat16(q2 * c + q1 * s);
    }
    {
        long kb = base + E_DIM;
        float k1 = __bfloat162float(qkv[kb]);
        float k2 = __bfloat162float(qkv[kb + 32]);
        qkv[kb]      = __float2bfloat16(k1 * c - k2 * s);
        qkv[kb + 32] = __float2bfloat16(k2 * c + k1 * s);
    }
}

// ---------------- V transpose: (T, h, d) -> (h*d, T) ----------------
__global__ __launch_bounds__(256) void vtrans_kernel(
    const __hip_bfloat16* __restrict__ qkv, __hip_bfloat16* __restrict__ vt, int T)
{
    long u = (long)blockIdx.x * 256 + threadIdx.x;
    int tchunks = T >> 3;
    int tc = (int)(u % tchunks);
    int hd = (int)(u / tchunks);
    if (hd >= E_DIM) return;
    long t0 = (long)tc * 8;
    bf8_t v;
    #pragma unroll
    for (int j = 0; j < 8; j++)
        v[j] = *(const short*)&qkv[(t0 + j) * QKV_LD + 2 * E_DIM + hd];
    *(bf8_t*)&vt[(long)hd * T + t0] = v;
}

// ---------------- flash attention: round-4 = 2-phase pipelined staging ----------------
// 1 block (256 thr) = 128 q-rows of one (seq, head). Round-3 kernel was latency-bound:
// all pipes sum to ~35us of a 173us kernel (MfmaUtil 16, VALU 37, occ 26) because each
// kv-tile paid the full global_load_lds latency behind a vmcnt(0)-draining syncthreads.
// This round: double-buffered K/V LDS (64 KB -> 2 blocks/CU), stage tile t+1 before
// computing tile t, ONE raw s_barrier + vmcnt/lgkmcnt drain per tile (T3-minimum
// 2-phase); s_setprio(1) around MFMA clusters (T5); defer-max rescale THR=8 (T13).
// S^T = K.Q^T; P^T feeds O^T = V^T.P^T from registers.
__global__ __launch_bounds__(256, 2) void attn_kernel(
    const __hip_bfloat16* __restrict__ qkv, const __hip_bfloat16* __restrict__ vt,
    const int* __restrict__ cu, __hip_bfloat16* __restrict__ obuf, int B, int T)
{
    __shared__ __align__(16) __hip_bfloat16 Ks[2][128 * 64];  // [key][d] swizzled, 2x16 KB
    __shared__ __align__(16) __hip_bfloat16 Vs[2][64 * 128];  // [d][key] swizzled, 2x16 KB

    int idx = blockIdx.x;
    int h = idx % NHEADS;
    int gt = idx / NHEADS;
    int b = 0, l = 0, seq0 = 0;
    for (; b < B; ++b) {
        seq0 = cu[b];
        l = cu[b + 1] - seq0;
        int ntile = (l + 127) >> 7;
        if (gt < ntile) break;
        gt -= ntile;
    }
    if (b == B) return;
    int q0 = gt * 128;

    const int t = threadIdx.x;
    const int wv = t >> 6, ln = t & 63;
    const int m16 = ln & 15, q4 = ln >> 4;

    // K: slot s2 -> row s2>>3, chunk (s2&7)^(row&7); V: row s2>>4, chunk (s2&15)^(row&15)
    auto stage_full = [&](int kv0n, int bi) {
        #pragma unroll
        for (int i = 0; i < 4; i++) {
            int s2 = i * 256 + t;
            int key = s2 >> 3, cg = (s2 & 7) ^ (key & 7);
            gl_lds16(qkv + (long)(seq0 + kv0n + key) * QKV_LD + E_DIM + h * HDIM + cg * 8,
                     (char*)&Ks[bi][0] + (size_t)(i * 256 + wv * 64) * 16);
        }
        #pragma unroll
        for (int i = 0; i < 4; i++) {
            int s2 = i * 256 + t;
            int d = s2 >> 4, cg = (s2 & 15) ^ (d & 15);
            gl_lds16(vt + (long)(h * HDIM + d) * T + seq0 + kv0n + cg * 8,
                     (char*)&Vs[bi][0] + (size_t)(i * 256 + wv * 64) * 16);
        }
    };
    auto stage_tail = [&](int kv0n, int bi) {   // dead in this workload (l % 128 == 0)
        #pragma unroll
        for (int i = 0; i < 4; i++) {
            int s2 = i * 256 + t;
            int key = s2 >> 3, c = s2 & 7;
            bf8_t v = (bf8_t)0;
            if (kv0n + key < l)
                v = *(const bf8_t*)(qkv + (long)(seq0 + kv0n + key) * QKV_LD + E_DIM + h * HDIM + c * 8);
            *(bf8_t*)&Ks[bi][key * 64 + (c ^ (key & 7)) * 8] = v;
        }
        #pragma unroll
        for (int i = 0; i < 4; i++) {
            int s2 = i * 256 + t;
            int d = s2 >> 4, c = s2 & 15;
            bf8_t v = (bf8_t)0;
            int tb = kv0n + c * 8;
            #pragma unroll
            for (int u = 0; u < 8; u++)
                if (tb + u < l)
                    v[u] = *(const short*)&vt[(long)(h * HDIM + d) * T + seq0 + tb + u];
            *(bf8_t*)&Vs[bi][d * 128 + (c ^ (d & 15)) * 8] = v;
        }
    };

    // prologue: issue staging of tile 0 first, then load Q while it flies
    if (128 <= l) stage_full(0, 0); else stage_tail(0, 0);

    // Q B-frags in registers: bq[nt][kc] = B[k=kc*32+q4*8+j][n=m16]
    bf8_t bq[2][2];
    #pragma unroll
    for (int nt = 0; nt < 2; nt++) {
        int qrow = q0 + wv * 32 + nt * 16 + m16;
        #pragma unroll
        for (int kc = 0; kc < 2; kc++) {
            bf8_t v = (bf8_t)0;
            if (qrow < l)
                v = *(const bf8_t*)(qkv + (long)(seq0 + qrow) * QKV_LD + h * HDIM + kc * 32 + q4 * 8);
            bq[nt][kc] = v;
        }
    }

    f4_t oacc[2][4] = {};
    float m_s[2] = {-1e30f, -1e30f};
    float l_s[2] = {0.0f, 0.0f};

    const int ksw0 = (q4 ^ (m16 & 7)) * 8;        // slot of global chunk q4
    const int ksw1 = ((4 + q4) ^ (m16 & 7)) * 8;  // slot of global chunk 4+q4

    asm volatile("s_waitcnt vmcnt(0) lgkmcnt(0)" ::: "memory");
    __builtin_amdgcn_s_barrier();

    int cur = 0;
    for (int kv0 = 0; kv0 < l; kv0 += 128) {
        const bool full = (kv0 + 128 <= l);
        const int kvn = kv0 + 128;
        const bool has_next = kvn < l;          // block-uniform
        if (has_next) {                          // issue next tile's loads NOW;
            if (kvn + 128 <= l) stage_full(kvn, cur ^ 1);   // latency hides under compute
            else stage_tail(kvn, cur ^ 1);
        }

        const __hip_bfloat16* Kb = Ks[cur];
        const __hip_bfloat16* Vb = Vs[cur];

        // S^T = K.Q^T : S[nt][mt] holds S^T[key=mt*16+q4*4+r][qrow=m16]
        f4_t S[2][8];
        __builtin_amdgcn_s_setprio(1);
        #pragma unroll
        for (int mt = 0; mt < 8; mt++) {
            const __hip_bfloat16* krow = &Kb[(mt * 16 + m16) * 64];
            bf8_t ak0 = *(const bf8_t*)(krow + ksw0);
            bf8_t ak1 = *(const bf8_t*)(krow + ksw1);
            #pragma unroll
            for (int nt = 0; nt < 2; nt++) {
                f4_t a = {};
                a = mfma16x32(ak0, bq[nt][0], a);
                a = mfma16x32(ak1, bq[nt][1], a);
                S[nt][mt] = a;
            }
        }
        __builtin_amdgcn_s_setprio(0);

        if (!full) {
            #pragma unroll
            for (int mt = 0; mt < 8; mt++) {
                #pragma unroll
                for (int r = 0; r < 4; r++) {
                    bool valid = (kv0 + mt * 16 + q4 * 4 + r) < l;
                    #pragma unroll
                    for (int nt = 0; nt < 2; nt++)
                        if (!valid) S[nt][mt][r] = -1e30f;
                }
            }
        }

        // online softmax (base-2 domain; log2e folded into Wq/bq) + defer-max (THR=8)
        #pragma unroll
        for (int nt = 0; nt < 2; nt++) {
            float mx = -1e30f;
            #pragma unroll
            for (int mt = 0; mt < 8; mt++)
                #pragma unroll
                for (int r = 0; r < 4; r++)
                    mx = fmaxf(mx, S[nt][mt][r]);
            mx = fmaxf(mx, __shfl_xor(mx, 16));
            mx = fmaxf(mx, __shfl_xor(mx, 32));
            // skip O/l rescale while max growth < 8: P bounded by 2^8, exact-arith
            // invariant (common inflation factor cancels in O = sum(pV)/sum(p))
            if (!__all(mx - m_s[nt] <= 8.0f)) {
                float mn = fmaxf(m_s[nt], mx);
                float al = exp2f(m_s[nt] - mn);
                m_s[nt] = mn;
                l_s[nt] *= al;
                #pragma unroll
                for (int dt = 0; dt < 4; dt++)
                    #pragma unroll
                    for (int r = 0; r < 4; r++)
                        oacc[nt][dt][r] *= al;
            }
            float mcur = m_s[nt];
            float ls = 0.0f;
            #pragma unroll
            for (int mt = 0; mt < 8; mt++) {
                #pragma unroll
                for (int r = 0; r < 4; r++) {
                    float p = exp2f(S[nt][mt][r] - mcur);
                    ls += p;
                    S[nt][mt][r] = p;
                }
            }
            l_s[nt] += ls;
        }

        // O^T += V^T . P^T  (A=V^T from swizzled LDS, B=P^T from regs)
        __builtin_amdgcn_s_setprio(1);
        #pragma unroll
        for (int mt = 0; mt < 8; mt++) {
            bf4_t bp[2];
            #pragma unroll
            for (int nt = 0; nt < 2; nt++) {
                bf4_t p;
                p[0] = f2bs(S[nt][mt][0]); p[1] = f2bs(S[nt][mt][1]);
                p[2] = f2bs(S[nt][mt][2]); p[3] = f2bs(S[nt][mt][3]);
                bp[nt] = p;
            }
            const int vsw = ((mt * 2 + (q4 >> 1)) ^ m16) * 8 + (q4 & 1) * 4;
            #pragma unroll
            for (int dt = 0; dt < 4; dt++) {
                bf4_t av = *(const bf4_t*)&Vb[(dt * 16 + m16) * 128 + vsw];
                #pragma unroll
                for (int nt = 0; nt < 2; nt++)
                    oacc[nt][dt] = mfma16x16(av, bp[nt], oacc[nt][dt]);
            }
        }
        __builtin_amdgcn_s_setprio(0);

        if (has_next) {
            // wait for next tile's staging (issued before compute -> mostly landed)
            // and make all waves' LDS writes visible; ONE barrier per tile.
            asm volatile("s_waitcnt vmcnt(0) lgkmcnt(0)" ::: "memory");
            __builtin_amdgcn_s_barrier();
            cur ^= 1;
        }
    }

    // finalize
    #pragma unroll
    for (int nt = 0; nt < 2; nt++) {
        float ls = l_s[nt];
        ls += __shfl_xor(ls, 16);
        ls += __shfl_xor(ls, 32);
        float inv = 1.0f / ls;
        int qrow = q0 + wv * 32 + nt * 16 + m16;
        if (qrow < l) {
            #pragma unroll
            for (int dt = 0; dt < 4; dt++) {
                bf4_t o;
                #pragma unroll
                for (int r = 0; r < 4; r++)
                    o[r] = f2bs(oacc[nt][dt][r] * inv);
                *(bf4_t*)&obuf[(long)(seq0 + qrow) * E_DIM + h * HDIM + dt * 16 + q4 * 4] = o;
            }
        }
    }
}

// ---------------- launch ----------------
extern "C" void kernel_launch(void* const* d_in, const int* in_sizes, int n_in,
                              void* d_out, int out_size, void* d_ws, size_t ws_size,
                              hipStream_t stream) {
    const int E = E_DIM;
    const int T = in_sizes[0] / E;      // 8192
    const int B = in_sizes[1] - 1;      // 8

    const float* x  = (const float*)d_in[0];
    const int*   cu = (const int*)d_in[1];
    const float* Wq = (const float*)d_in[3];
    const float* bq = (const float*)d_in[4];
    const float* Wk = (const float*)d_in[5];
    const float* bk = (const float*)d_in[6];
    const float* Wv = (const float*)d_in[7];
    const float* bv = (const float*)d_in[8];
    const float* Wo = (const float*)d_in[9];
    const float* bo = (const float*)d_in[10];

    char* ws = (char*)d_ws;
    size_t off = 0;
    auto alloc = [&](size_t bytes) -> void* {
        void* p = ws + off;
        off = (off + bytes + 255) & ~(size_t)255;
        return p;
    };
    __hip_bfloat16* xbf   = (__hip_bfloat16*)alloc((size_t)T * E * 2);
    __hip_bfloat16* wqkv  = (__hip_bfloat16*)alloc((size_t)3 * E * E * 2);
    __hip_bfloat16* wobf  = (__hip_bfloat16*)alloc((size_t)E * E * 2);
    float*          bqkv  = (float*)alloc((size_t)3 * E * 4);
    __hip_bfloat16* qkvb  = (__hip_bfloat16*)alloc((size_t)T * 3 * E * 2);
    __hip_bfloat16* vt    = (__hip_bfloat16*)alloc((size_t)E * T * 2);
    __hip_bfloat16* obuf  = xbf;  // alias: x_bf dead after QKV GEMM

    long nx8 = (long)T * E / 8;
    long nw8 = (long)E * E / 8;
    long nb8 = (long)3 * E / 8;
    long total = nx8 + 4 * nw8 + nb8;
    int pblocks = (int)((total + 255) / 256);
    prep_kernel<<<pblocks, 256, 0, stream>>>(x, Wq, Wk, Wv, Wo, bq, bk, bv,
                                             xbf, wqkv, wobf, bqkv, nx8, nw8, nb8);

    gemm_nt<true><<<dim3(3 * E / 128, T / 128), 256, 0, stream>>>(
        xbf, wqkv, bqkv, qkvb, T, 3 * E, E, 3 * E);

    rope_kernel<<<(int)(((long)T * NHEADS * 32) / 256), 256, 0, stream>>>(qkvb, cu, B, T);

    vtrans_kernel<<<(int)(((long)E * T / 8 + 255) / 256), 256, 0, stream>>>(qkvb, vt, T);

    // 128-row q-tiles: upper bound on sum of per-seq ceil(l/128)
    int qtiles_ub = T / 128 + B;
    attn_kernel<<<qtiles_ub * NHEADS, 256, 0, stream>>>(qkvb, vt, cu, obuf, B, T);

    gemm_nt<false><<<dim3(E / 128, T / 128), 256, 0, stream>>>(
        obuf, wobf, bo, d_out, T, E, E, E);
}

// Round 2
// 428.042 us; speedup vs baseline: 1.1923x; 1.0487x over previous
//
#include <hip/hip_runtime.h>
#include <hip/hip_bf16.h>
#include <cstdint>

#define E_DIM   1280
#define NHEADS  20
#define HDIM    64
#define QKV_LD  3840   // 3*E

typedef __attribute__((ext_vector_type(8))) short bf8_t;   // 8 bf16 (4 VGPRs)
typedef __attribute__((ext_vector_type(4))) short bf4_t;   // 4 bf16 (2 VGPRs)
typedef __attribute__((ext_vector_type(4))) float f4_t;    // MFMA accumulator

__device__ __forceinline__ short f2bs(float f) {
    union { __hip_bfloat16 h; short s; } u;
    u.h = __float2bfloat16(f);
    return u.s;
}

__device__ __forceinline__ f4_t mfma16x32(bf8_t a, bf8_t b, f4_t c) {
    return __builtin_amdgcn_mfma_f32_16x16x32_bf16(a, b, c, 0, 0, 0);
}
__device__ __forceinline__ f4_t mfma16x16(bf4_t a, bf4_t b, f4_t c) {
    return __builtin_amdgcn_mfma_f32_16x16x16bf16_1k(a, b, c, 0, 0, 0);
}

// async global->LDS, 16B per lane. LDS dest is wave-uniform base + lane*16.
__device__ __forceinline__ void gl_lds16(const void* g, void* l) {
    auto gp = reinterpret_cast<__attribute__((address_space(1))) unsigned int*>(
        reinterpret_cast<uintptr_t>(g));
    auto lp = reinterpret_cast<__attribute__((address_space(3))) unsigned int*>(
        reinterpret_cast<uintptr_t>(l));
    __builtin_amdgcn_global_load_lds(gp, lp, 16, 0, 0);
}

// ---------------- prep: casts + weight concat + bias concat ----------------
// Wq/bq scale = d^-0.5 * log2(e): softmax computed in base-2 domain (exp2f).
#define QSCALE 0.18033688011112042f

__device__ __forceinline__ void cvt8(__hip_bfloat16* dst, const float* src, float sc) {
    float4 a = *(const float4*)src;
    float4 b = *(const float4*)(src + 4);
    bf8_t v;
    v[0] = f2bs(a.x * sc); v[1] = f2bs(a.y * sc); v[2] = f2bs(a.z * sc); v[3] = f2bs(a.w * sc);
    v[4] = f2bs(b.x * sc); v[5] = f2bs(b.y * sc); v[6] = f2bs(b.z * sc); v[7] = f2bs(b.w * sc);
    *(bf8_t*)dst = v;
}

__global__ __launch_bounds__(256) void prep_kernel(
    const float* __restrict__ x,
    const float* __restrict__ wq, const float* __restrict__ wk,
    const float* __restrict__ wv, const float* __restrict__ wo,
    const float* __restrict__ bq, const float* __restrict__ bk, const float* __restrict__ bv,
    __hip_bfloat16* __restrict__ xbf, __hip_bfloat16* __restrict__ wqkv,
    __hip_bfloat16* __restrict__ wobf, float* __restrict__ bqkv,
    long nx8, long nw8, long nb8)
{
    long u = (long)blockIdx.x * 256 + threadIdx.x;
    if (u < nx8) { cvt8(xbf + u * 8, x + u * 8, 1.0f); return; }
    u -= nx8;
    if (u < 3 * nw8) {
        long e = u * 8;
        long w1 = nw8 * 8;
        const float* src; float sc;
        if (e < w1)            { src = wq + e;           sc = QSCALE; }
        else if (e < 2 * w1)   { src = wk + (e - w1);    sc = 1.0f; }
        else                   { src = wv + (e - 2*w1);  sc = 1.0f; }
        cvt8(wqkv + e, src, sc);
        return;
    }
    u -= 3 * nw8;
    if (u < nw8) { cvt8(wobf + u * 8, wo + u * 8, 1.0f); return; }
    u -= nw8;
    if (u < nb8) {
        long e = u * 8;
        #pragma unroll
        for (int j = 0; j < 8; j++) {
            long i = e + j;
            float v;
            if (i < E_DIM)           v = bq[i] * QSCALE;
            else if (i < 2 * E_DIM)  v = bk[i - E_DIM];
            else                     v = bv[i - 2 * E_DIM];
            bqkv[i] = v;
        }
    }
}

// ---------------- m97-style NT GEMM (kept for output proj): C = A*B^T + bias ----------------
template<bool BF16_OUT>
__global__ __launch_bounds__(256, 3) void gemm_nt(
    const __hip_bfloat16* __restrict__ A, const __hip_bfloat16* __restrict__ Bw,
    const float* __restrict__ bias, void* __restrict__ Cout,
    int M, int N, int K, int ldc)
{
    __shared__ __align__(16) __hip_bfloat16 As[128 * 32];
    __shared__ __align__(16) __hip_bfloat16 Bs[128 * 32];
    const int t = threadIdx.x;
    const int wv = t >> 6;
    const int ln = t & 63;
    const int m16 = ln & 15, q4 = ln >> 4;
    const int row0 = blockIdx.y * 128, col0 = blockIdx.x * 128;
    const int wm = (wv >> 1) * 64, wn = (wv & 1) * 64;

    f4_t acc[4][4] = {};

    for (int k0 = 0; k0 < K; k0 += 32) {
        #pragma unroll
        for (int i = 0; i < 2; i++) {
            int s = i * 256 + t;
            int r = s >> 2, c = s & 3;
            gl_lds16(A + (size_t)(row0 + r) * K + k0 + c * 8,
                     As + (size_t)(i * 256 + wv * 64) * 8);
        }
        #pragma unroll
        for (int i = 0; i < 2; i++) {
            int s = i * 256 + t;
            int r = s >> 2, c = s & 3;
            gl_lds16(Bw + (size_t)(col0 + r) * K + k0 + c * 8,
                     Bs + (size_t)(i * 256 + wv * 64) * 8);
        }
        __syncthreads();
        bf8_t af[4], bfr[4];
        #pragma unroll
        for (int mt = 0; mt < 4; mt++)
            af[mt] = *(const bf8_t*)&As[(wm + mt * 16 + m16) * 32 + q4 * 8];
        #pragma unroll
        for (int nt = 0; nt < 4; nt++)
            bfr[nt] = *(const bf8_t*)&Bs[(wn + nt * 16 + m16) * 32 + q4 * 8];
        #pragma unroll
        for (int mt = 0; mt < 4; mt++)
            #pragma unroll
            for (int nt = 0; nt < 4; nt++)
                acc[mt][nt] = mfma16x32(af[mt], bfr[nt], acc[mt][nt]);
        __syncthreads();
    }

    #pragma unroll
    for (int nt = 0; nt < 4; nt++) {
        int cg = col0 + wn + nt * 16 + m16;
        float bv = bias[cg];
        #pragma unroll
        for (int mt = 0; mt < 4; mt++) {
            #pragma unroll
            for (int r = 0; r < 4; r++) {
                int rg = row0 + wm + mt * 16 + q4 * 4 + r;
                float v = acc[mt][nt][r] + bv;
                if constexpr (BF16_OUT)
                    ((__hip_bfloat16*)Cout)[(long)rg * ldc + cg] = __float2bfloat16(v);
                else
                    ((float*)Cout)[(long)rg * ldc + cg] = v;
            }
        }
    }
}

// ---------------- 256x256 pipelined NT GEMM (T1+T2+T3/T4+T5 stack) ----------------
// 512 thr = 8 waves (2M x 4N), per-wave 128x64 out, BK=64, dbuf LDS 128 KB (1 blk/CU).
// T2: chunk-XOR swizzle slot = chunk^(row&7) on both staging source and ds_read.
// T3/T4: stage tile kt+2 AFTER post-compute barrier (race-free: all slot reads
// completed before their MFMAs, which precede the barrier), then counted vmcnt(8):
// tile kt+1's 8 loads land, tile kt+2's 8 stay in flight across the barrier.
// T5: setprio(1) around each 16-MFMA quadrant cluster; quadrant order reuses frags
// (8/4/8/4 ds_reads interleaved with MFMA clusters).
template<bool BF16_OUT>
__global__ __launch_bounds__(512, 2) void gemm256(
    const __hip_bfloat16* __restrict__ A, const __hip_bfloat16* __restrict__ Bw,
    const float* __restrict__ bias, void* __restrict__ Cout,
    int M, int N, int K, int ldc)
{
    __shared__ __align__(16) __hip_bfloat16 As[2][256 * 64];  // 2 x 32 KB
    __shared__ __align__(16) __hip_bfloat16 Bs[2][256 * 64];  // 2 x 32 KB

    const int t = threadIdx.x;
    const int wv = t >> 6, ln = t & 63;
    const int m16 = ln & 15, q4 = ln >> 4;
    const int wr = wv >> 2, wc = wv & 3;   // 2 x 4 wave grid

    const int gx = N >> 8;
    const int nwg = gridDim.x;
    const int id = blockIdx.x;
    const int swz = ((nwg & 7) == 0) ? (id & 7) * (nwg >> 3) + (id >> 3) : id;  // T1 (bijective: nwg%8==0)
    const int col0 = (swz % gx) << 8;
    const int row0 = (swz / gx) << 8;

    const int NT = K >> 6;   // K-tiles of 64

    // stage one 256x64 tile: linear LDS dest (slot order), inverse-swizzled global src
    auto stage = [&](const __hip_bfloat16* src, __hip_bfloat16* dst) {
        #pragma unroll
        for (int i = 0; i < 4; i++) {
            int s = i * 512 + t;
            int r = s >> 3, c = (s & 7) ^ (r & 7);
            gl_lds16(src + (size_t)r * K + c * 8,
                     (char*)dst + (size_t)(i * 512 + wv * 64) * 16);
        }
    };

    // prologue: tiles 0 and 1
    stage(A  + (size_t)row0 * K,      &As[0][0]);
    stage(Bw + (size_t)col0 * K,      &Bs[0][0]);
    if (NT > 1) {
        stage(A  + (size_t)row0 * K + 64, &As[1][0]);
        stage(Bw + (size_t)col0 * K + 64, &Bs[1][0]);
        asm volatile("s_waitcnt vmcnt(8)" ::: "memory");   // tile 0 landed; tile 1 in flight
    } else {
        asm volatile("s_waitcnt vmcnt(0)" ::: "memory");
    }
    __builtin_amdgcn_s_barrier();

    f4_t acc[8][4] = {};

    for (int kt = 0; kt < NT; kt++) {
        const __hip_bfloat16* Ab = &As[kt & 1][0];
        const __hip_bfloat16* Bb = &Bs[kt & 1][0];

        auto lda = [&](const __hip_bfloat16* base, int r, int kc) {
            return *(const bf8_t*)&base[r * 64 + ((((kc << 2) | q4) ^ (r & 7)) << 3)];
        };

        bf8_t afr[4][2], bf0[2][2], bf1[2][2];
        // Q(mh0,nh0): af half 0 (8 reads) + bf half 0 (4 reads)
        #pragma unroll
        for (int mt = 0; mt < 4; mt++)
            #pragma unroll
            for (int kc = 0; kc < 2; kc++)
                afr[mt][kc] = lda(Ab, wr * 128 + mt * 16 + m16, kc);
        #pragma unroll
        for (int nt = 0; nt < 2; nt++)
            #pragma unroll
            for (int kc = 0; kc < 2; kc++)
                bf0[nt][kc] = lda(Bb, wc * 64 + nt * 16 + m16, kc);

        __builtin_amdgcn_s_setprio(1);
        #pragma unroll
        for (int mt = 0; mt < 4; mt++)
            #pragma unroll
            for (int nt = 0; nt < 2; nt++)
                #pragma unroll
                for (int kc = 0; kc < 2; kc++)
                    acc[mt][nt] = mfma16x32(afr[mt][kc], bf0[nt][kc], acc[mt][nt]);
        __builtin_amdgcn_s_setprio(0);

        // Q(mh0,nh1): new bf half 1 (4 reads)
        #pragma unroll
        for (int nt = 0; nt < 2; nt++)
            #pragma unroll
            for (int kc = 0; kc < 2; kc++)
                bf1[nt][kc] = lda(Bb, wc * 64 + (2 + nt) * 16 + m16, kc);

        __builtin_amdgcn_s_setprio(1);
        #pragma unroll
        for (int mt = 0; mt < 4; mt++)
            #pragma unroll
            for (int nt = 0; nt < 2; nt++)
                #pragma unroll
                for (int kc = 0; kc < 2; kc++)
                    acc[mt][2 + nt] = mfma16x32(afr[mt][kc], bf1[nt][kc], acc[mt][2 + nt]);
        __builtin_amdgcn_s_setprio(0);

        // Q(mh1,nh1): new af half 1 (8 reads)
        #pragma unroll
        for (int mt = 0; mt < 4; mt++)
            #pragma unroll
            for (int kc = 0; kc < 2; kc++)
                afr[mt][kc] = lda(Ab, wr * 128 + (4 + mt) * 16 + m16, kc);

        __builtin_amdgcn_s_setprio(1);
        #pragma unroll
        for (int mt = 0; mt < 4; mt++)
            #pragma unroll
            for (int nt = 0; nt < 2; nt++)
                #pragma unroll
                for (int kc = 0; kc < 2; kc++)
                    acc[4 + mt][2 + nt] = mfma16x32(afr[mt][kc], bf1[nt][kc], acc[4 + mt][2 + nt]);
        __builtin_amdgcn_s_setprio(0);

        // Q(mh1,nh0): bf half 0 still live
        __builtin_amdgcn_s_setprio(1);
        #pragma unroll
        for (int mt = 0; mt < 4; mt++)
            #pragma unroll
            for (int nt = 0; nt < 2; nt++)
                #pragma unroll
                for (int kc = 0; kc < 2; kc++)
                    acc[4 + mt][nt] = mfma16x32(afr[mt][kc], bf0[nt][kc], acc[4 + mt][nt]);
        __builtin_amdgcn_s_setprio(0);

        // all reads of slot kt&1 done (per-wave lgkmcnt before MFMA; barrier -> all waves)
        asm volatile("s_waitcnt lgkmcnt(0)" ::: "memory");
        __builtin_amdgcn_s_barrier();

        if (kt + 2 < NT) {   // restage the just-freed slot for tile kt+2
            stage(A  + (size_t)row0 * K + (size_t)(kt + 2) * 64, &As[kt & 1][0]);
            stage(Bw + (size_t)col0 * K + (size_t)(kt + 2) * 64, &Bs[kt & 1][0]);
        }
        if (kt + 1 < NT) {
            if (kt + 2 < NT)
                asm volatile("s_waitcnt vmcnt(8)" ::: "memory");  // tile kt+1 landed; kt+2 in flight
            else
                asm volatile("s_waitcnt vmcnt(0)" ::: "memory");  // drain last tile
            __builtin_amdgcn_s_barrier();
        }
    }

    #pragma unroll
    for (int nt = 0; nt < 4; nt++) {
        int cg = col0 + wc * 64 + nt * 16 + m16;
        float bval = bias[cg];
        #pragma unroll
        for (int mt = 0; mt < 8; mt++) {
            #pragma unroll
            for (int r = 0; r < 4; r++) {
                int rg = row0 + wr * 128 + mt * 16 + q4 * 4 + r;
                float v = acc[mt][nt][r] + bval;
                if constexpr (BF16_OUT)
                    ((__hip_bfloat16*)Cout)[(long)rg * ldc + cg] = __float2bfloat16(v);
                else
                    ((float*)Cout)[(long)rg * ldc + cg] = v;
            }
        }
    }
}

// ---------------- RoPE (in place on q,k sections of qkv) ----------------
__global__ __launch_bounds__(256) void rope_kernel(
    __hip_bfloat16* __restrict__ qkv, const int* __restrict__ cu, int B, int T)
{
    long idx = (long)blockIdx.x * 256 + threadIdx.x;
    int i = idx & 31;
    long r = idx >> 5;
    int h = (int)(r % NHEADS);
    int tok = (int)(r / NHEADS);
    if (tok >= T) return;
    int pos = tok;
    for (int b = 1; b <= B; b++) if (tok >= cu[b]) pos = tok - cu[b];
    float f = (float)pos * exp2f(-(float)i * 0.41524100558003436f);
    float s, c;
    sincosf(f, &s, &c);
    long base = (long)tok * QKV_LD + h * HDIM + i;
    {
        float q1 = __bfloat162float(qkv[base]);
        float q2 = __bfloat162float(qkv[base + 32]);
        qkv[base]      = __float2bfloat16(q1 * c - q2 * s);
        qkv[base + 32] = __float2bfloat16(q2 * c + q1 * s);
    }
    {
        long kb = base + E_DIM;
        float k1 = __bfloat162float(qkv[kb]);
        float k2 = __bfloat162float(qkv[kb + 32]);
        qkv[kb]      = __float2bfloat16(k1 * c - k2 * s);
        qkv[kb + 32] = __float2bfloat16(k2 * c + k1 * s);
    }
}

// ---------------- V transpose: (T, h, d) -> (h*d, T) ----------------
__global__ __launch_bounds__(256) void vtrans_kernel(
    const __hip_bfloat16* __restrict__ qkv, __hip_bfloat16* __restrict__ vt, int T)
{
    long u = (long)blockIdx.x * 256 + threadIdx.x;
    int tchunks = T >> 3;
    int tc = (int)(u % tchunks);
    int hd = (int)(u / tchunks);
    if (hd >= E_DIM) return;
    long t0 = (long)tc * 8;
    bf8_t v;
    #pragma unroll
    for (int j = 0; j < 8; j++)
        v[j] = *(const short*)&qkv[(t0 + j) * QKV_LD + 2 * E_DIM + hd];
    *(bf8_t*)&vt[(long)hd * T + t0] = v;
}

// ---------------- flash attention: 2-phase pipelined staging (round 4) ----------------
__global__ __launch_bounds__(256, 2) void attn_kernel(
    const __hip_bfloat16* __restrict__ qkv, const __hip_bfloat16* __restrict__ vt,
    const int* __restrict__ cu, __hip_bfloat16* __restrict__ obuf, int B, int T)
{
    __shared__ __align__(16) __hip_bfloat16 Ks[2][128 * 64];  // [key][d] swizzled, 2x16 KB
    __shared__ __align__(16) __hip_bfloat16 Vs[2][64 * 128];  // [d][key] swizzled, 2x16 KB

    int idx = blockIdx.x;
    int h = idx % NHEADS;
    int gt = idx / NHEADS;
    int b = 0, l = 0, seq0 = 0;
    for (; b < B; ++b) {
        seq0 = cu[b];
        l = cu[b + 1] - seq0;
        int ntile = (l + 127) >> 7;
        if (gt < ntile) break;
        gt -= ntile;
    }
    if (b == B) return;
    int q0 = gt * 128;

    const int t = threadIdx.x;
    const int wv = t >> 6, ln = t & 63;
    const int m16 = ln & 15, q4 = ln >> 4;

    // K: slot s2 -> row s2>>3, chunk (s2&7)^(row&7); V: row s2>>4, chunk (s2&15)^(row&15)
    auto stage_full = [&](int kv0n, int bi) {
        #pragma unroll
        for (int i = 0; i < 4; i++) {
            int s2 = i * 256 + t;
            int key = s2 >> 3, cg = (s2 & 7) ^ (key & 7);
            gl_lds16(qkv + (long)(seq0 + kv0n + key) * QKV_LD + E_DIM + h * HDIM + cg * 8,
                     (char*)&Ks[bi][0] + (size_t)(i * 256 + wv * 64) * 16);
        }
        #pragma unroll
        for (int i = 0; i < 4; i++) {
            int s2 = i * 256 + t;
            int d = s2 >> 4, cg = (s2 & 15) ^ (d & 15);
            gl_lds16(vt + (long)(h * HDIM + d) * T + seq0 + kv0n + cg * 8,
                     (char*)&Vs[bi][0] + (size_t)(i * 256 + wv * 64) * 16);
        }
    };
    auto stage_tail = [&](int kv0n, int bi) {   // dead in this workload (l % 128 == 0)
        #pragma unroll
        for (int i = 0; i < 4; i++) {
            int s2 = i * 256 + t;
            int key = s2 >> 3, c = s2 & 7;
            bf8_t v = (bf8_t)0;
            if (kv0n + key < l)
                v = *(const bf8_t*)(qkv + (long)(seq0 + kv0n + key) * QKV_LD + E_DIM + h * HDIM + c * 8);
            *(bf8_t*)&Ks[bi][key * 64 + (c ^ (key & 7)) * 8] = v;
        }
        #pragma unroll
        for (int i = 0; i < 4; i++) {
            int s2 = i * 256 + t;
            int d = s2 >> 4, c = s2 & 15;
            bf8_t v = (bf8_t)0;
            int tb = kv0n + c * 8;
            #pragma unroll
            for (int u = 0; u < 8; u++)
                if (tb + u < l)
                    v[u] = *(const short*)&vt[(long)(h * HDIM + d) * T + seq0 + tb + u];
            *(bf8_t*)&Vs[bi][d * 128 + (c ^ (d & 15)) * 8] = v;
        }
    };

    // prologue: issue staging of tile 0 first, then load Q while it flies
    if (128 <= l) stage_full(0, 0); else stage_tail(0, 0);

    // Q B-frags in registers: bq[nt][kc] = B[k=kc*32+q4*8+j][n=m16]
    bf8_t bq[2][2];
    #pragma unroll
    for (int nt = 0; nt < 2; nt++) {
        int qrow = q0 + wv * 32 + nt * 16 + m16;
        #pragma unroll
        for (int kc = 0; kc < 2; kc++) {
            bf8_t v = (bf8_t)0;
            if (qrow < l)
                v = *(const bf8_t*)(qkv + (long)(seq0 + qrow) * QKV_LD + h * HDIM + kc * 32 + q4 * 8);
            bq[nt][kc] = v;
        }
    }

    f4_t oacc[2][4] = {};
    float m_s[2] = {-1e30f, -1e30f};
    float l_s[2] = {0.0f, 0.0f};

    const int ksw0 = (q4 ^ (m16 & 7)) * 8;        // slot of global chunk q4
    const int ksw1 = ((4 + q4) ^ (m16 & 7)) * 8;  // slot of global chunk 4+q4

    asm volatile("s_waitcnt vmcnt(0) lgkmcnt(0)" ::: "memory");
    __builtin_amdgcn_s_barrier();

    int cur = 0;
    for (int kv0 = 0; kv0 < l; kv0 += 128) {
        const bool full = (kv0 + 128 <= l);
        const int kvn = kv0 + 128;
        const bool has_next = kvn < l;          // block-uniform
        if (has_next) {                          // issue next tile's loads NOW;
            if (kvn + 128 <= l) stage_full(kvn, cur ^ 1);   // latency hides under compute
            else stage_tail(kvn, cur ^ 1);
        }

        const __hip_bfloat16* Kb = Ks[cur];
        const __hip_bfloat16* Vb = Vs[cur];

        // S^T = K.Q^T : S[nt][mt] holds S^T[key=mt*16+q4*4+r][qrow=m16]
        f4_t S[2][8];
        __builtin_amdgcn_s_setprio(1);
        #pragma unroll
        for (int mt = 0; mt < 8; mt++) {
            const __hip_bfloat16* krow = &Kb[(mt * 16 + m16) * 64];
            bf8_t ak0 = *(const bf8_t*)(krow + ksw0);
            bf8_t ak1 = *(const bf8_t*)(krow + ksw1);
            #pragma unroll
            for (int nt = 0; nt < 2; nt++) {
                f4_t a = {};
                a = mfma16x32(ak0, bq[nt][0], a);
                a = mfma16x32(ak1, bq[nt][1], a);
                S[nt][mt] = a;
            }
        }
        __builtin_amdgcn_s_setprio(0);

        if (!full) {
            #pragma unroll
            for (int mt = 0; mt < 8; mt++) {
                #pragma unroll
                for (int r = 0; r < 4; r++) {
                    bool valid = (kv0 + mt * 16 + q4 * 4 + r) < l;
                    #pragma unroll
                    for (int nt = 0; nt < 2; nt++)
                        if (!valid) S[nt][mt][r] = -1e30f;
                }
            }
        }

        // online softmax (base-2 domain; log2e folded into Wq/bq) + defer-max (THR=8)
        #pragma unroll
        for (int nt = 0; nt < 2; nt++) {
            float mx = -1e30f;
            #pragma unroll
            for (int mt = 0; mt < 8; mt++)
                #pragma unroll
                for (int r = 0; r < 4; r++)
                    mx = fmaxf(mx, S[nt][mt][r]);
            mx = fmaxf(mx, __shfl_xor(mx, 16));
            mx = fmaxf(mx, __shfl_xor(mx, 32));
            // skip O/l rescale while max growth < 8: P bounded by 2^8, exact-arith
            // invariant (common inflation factor cancels in O = sum(pV)/sum(p))
            if (!__all(mx - m_s[nt] <= 8.0f)) {
                float mn = fmaxf(m_s[nt], mx);
                float al = exp2f(m_s[nt] - mn);
                m_s[nt] = mn;
                l_s[nt] *= al;
                #pragma unroll
                for (int dt = 0; dt < 4; dt++)
                    #pragma unroll
                    for (int r = 0; r < 4; r++)
                        oacc[nt][dt][r] *= al;
            }
            float mcur = m_s[nt];
            float ls = 0.0f;
            #pragma unroll
            for (int mt = 0; mt < 8; mt++) {
                #pragma unroll
                for (int r = 0; r < 4; r++) {
                    float p = exp2f(S[nt][mt][r] - mcur);
                    ls += p;
                    S[nt][mt][r] = p;
                }
            }
            l_s[nt] += ls;
        }

        // O^T += V^T . P^T  (A=V^T from swizzled LDS, B=P^T from regs)
        __builtin_amdgcn_s_setprio(1);
        #pragma unroll
        for (int mt = 0; mt < 8; mt++) {
            bf4_t bp[2];
            #pragma unroll
            for (int nt = 0; nt < 2; nt++) {
                bf4_t p;
                p[0] = f2bs(S[nt][mt][0]); p[1] = f2bs(S[nt][mt][1]);
                p[2] = f2bs(S[nt][mt][2]); p[3] = f2bs(S[nt][mt][3]);
                bp[nt] = p;
            }
            const int vsw = ((mt * 2 + (q4 >> 1)) ^ m16) * 8 + (q4 & 1) * 4;
            #pragma unroll
            for (int dt = 0; dt < 4; dt++) {
                bf4_t av = *(const bf4_t*)&Vb[(dt * 16 + m16) * 128 + vsw];
                #pragma unroll
                for (int nt = 0; nt < 2; nt++)
                    oacc[nt][dt] = mfma16x16(av, bp[nt], oacc[nt][dt]);
            }
        }
        __builtin_amdgcn_s_setprio(0);

        if (has_next) {
            // wait for next tile's staging (issued before compute -> mostly landed)
            // and make all waves' LDS writes visible; ONE barrier per tile.
            asm volatile("s_waitcnt vmcnt(0) lgkmcnt(0)" ::: "memory");
            __builtin_amdgcn_s_barrier();
            cur ^= 1;
        }
    }

    // finalize
    #pragma unroll
    for (int nt = 0; nt < 2; nt++) {
        float ls = l_s[nt];
        ls += __shfl_xor(ls, 16);
        ls += __shfl_xor(ls, 32);
        float inv = 1.0f / ls;
        int qrow = q0 + wv * 32 + nt * 16 + m16;
        if (qrow < l) {
            #pragma unroll
            for (int dt = 0; dt < 4; dt++) {
                bf4_t o;
                #pragma unroll
                for (int r = 0; r < 4; r++)
                    o[r] = f2bs(oacc[nt][dt][r] * inv);
                *(bf4_t*)&obuf[(long)(seq0 + qrow) * E_DIM + h * HDIM + dt * 16 + q4 * 4] = o;
            }
        }
    }
}

// ---------------- launch ----------------
extern "C" void kernel_launch(void* const* d_in, const int* in_sizes, int n_in,
                              void* d_out, int out_size, void* d_ws, size_t ws_size,
                              hipStream_t stream) {
    const int E = E_DIM;
    const int T = in_sizes[0] / E;      // 8192
    const int B = in_sizes[1] - 1;      // 8

    const float* x  = (const float*)d_in[0];
    const int*   cu = (const int*)d_in[1];
    const float* Wq = (const float*)d_in[3];
    const float* bq = (const float*)d_in[4];
    const float* Wk = (const float*)d_in[5];
    const float* bk = (const float*)d_in[6];
    const float* Wv = (const float*)d_in[7];
    const float* bv = (const float*)d_in[8];
    const float* Wo = (const float*)d_in[9];
    const float* bo = (const float*)d_in[10];

    char* ws = (char*)d_ws;
    size_t off = 0;
    auto alloc = [&](size_t bytes) -> void* {
        void* p = ws + off;
        off = (off + bytes + 255) & ~(size_t)255;
        return p;
    };
    __hip_bfloat16* xbf   = (__hip_bfloat16*)alloc((size_t)T * E * 2);
    __hip_bfloat16* wqkv  = (__hip_bfloat16*)alloc((size_t)3 * E * E * 2);
    __hip_bfloat16* wobf  = (__hip_bfloat16*)alloc((size_t)E * E * 2);
    float*          bqkv  = (float*)alloc((size_t)3 * E * 4);
    __hip_bfloat16* qkvb  = (__hip_bfloat16*)alloc((size_t)T * 3 * E * 2);
    __hip_bfloat16* vt    = (__hip_bfloat16*)alloc((size_t)E * T * 2);
    __hip_bfloat16* obuf  = xbf;  // alias: x_bf dead after QKV GEMM

    long nx8 = (long)T * E / 8;
    long nw8 = (long)E * E / 8;
    long nb8 = (long)3 * E / 8;
    long total = nx8 + 4 * nw8 + nb8;
    int pblocks = (int)((total + 255) / 256);
    prep_kernel<<<pblocks, 256, 0, stream>>>(x, Wq, Wk, Wv, Wo, bq, bk, bv,
                                             xbf, wqkv, wobf, bqkv, nx8, nw8, nb8);

    // QKV projection: 256^2-tile pipelined GEMM (T=8192, 3E=3840 both /256)
    gemm256<true><<<(T / 256) * (3 * E / 256), 512, 0, stream>>>(
        xbf, wqkv, bqkv, qkvb, T, 3 * E, E, 3 * E);

    rope_kernel<<<(int)(((long)T * NHEADS * 32) / 256), 256, 0, stream>>>(qkvb, cu, B, T);

    vtrans_kernel<<<(int)(((long)E * T / 8 + 255) / 256), 256, 0, stream>>>(qkvb, vt, T);

    // 128-row q-tiles: upper bound on sum of per-seq ceil(l/128)
    int qtiles_ub = T / 128 + B;
    attn_kernel<<<qtiles_ub * NHEADS, 256, 0, stream>>>(qkvb, vt, cu, obuf, B, T);

    // output projection: N=1280 -> only 160 blocks at 256^2; keep 128^2 (640 blocks)
    gemm_nt<false><<<dim3(E / 128, T / 128), 256, 0, stream>>>(
        obuf, wobf, bo, d_out, T, E, E, E);
}

// Round 3
// 385.863 us; speedup vs baseline: 1.3227x; 1.1093x over previous
//
#include <hip/hip_runtime.h>
#include <hip/hip_bf16.h>
#include <cstdint>

#define E_DIM   1280
#define NHEADS  20
#define HDIM    64
#define QKV_LD  3840   // 3*E

typedef __attribute__((ext_vector_type(8))) short bf8_t;   // 8 bf16 (4 VGPRs)
typedef __attribute__((ext_vector_type(4))) short bf4_t;   // 4 bf16 (2 VGPRs)
typedef __attribute__((ext_vector_type(4))) float f4_t;    // MFMA accumulator

__device__ __forceinline__ short f2bs(float f) {
    union { __hip_bfloat16 h; short s; } u;
    u.h = __float2bfloat16(f);
    return u.s;
}

// hardware packed f32x2 -> bf16x2 (RNE), T12 recipe: no builtin on gfx950
__device__ __forceinline__ bf4_t pk4(f4_t s) {
    union { bf4_t v; uint32_t u[2]; } r;
    asm("v_cvt_pk_bf16_f32 %0, %1, %2" : "=v"(r.u[0]) : "v"(s[0]), "v"(s[1]));
    asm("v_cvt_pk_bf16_f32 %0, %1, %2" : "=v"(r.u[1]) : "v"(s[2]), "v"(s[3]));
    return r.v;
}

__device__ __forceinline__ f4_t mfma16x32(bf8_t a, bf8_t b, f4_t c) {
    return __builtin_amdgcn_mfma_f32_16x16x32_bf16(a, b, c, 0, 0, 0);
}
__device__ __forceinline__ f4_t mfma16x16(bf4_t a, bf4_t b, f4_t c) {
    return __builtin_amdgcn_mfma_f32_16x16x16bf16_1k(a, b, c, 0, 0, 0);
}

// async global->LDS, 16B per lane. LDS dest is wave-uniform base + lane*16.
__device__ __forceinline__ void gl_lds16(const void* g, void* l) {
    auto gp = reinterpret_cast<__attribute__((address_space(1))) unsigned int*>(
        reinterpret_cast<uintptr_t>(g));
    auto lp = reinterpret_cast<__attribute__((address_space(3))) unsigned int*>(
        reinterpret_cast<uintptr_t>(l));
    __builtin_amdgcn_global_load_lds(gp, lp, 16, 0, 0);
}

// ---------------- prep: casts + weight concat + bias concat ----------------
// Wq/bq scale = d^-0.5 * log2(e): softmax computed in base-2 domain (exp2f).
#define QSCALE 0.18033688011112042f

__device__ __forceinline__ void cvt8(__hip_bfloat16* dst, const float* src, float sc) {
    float4 a = *(const float4*)src;
    float4 b = *(const float4*)(src + 4);
    bf8_t v;
    v[0] = f2bs(a.x * sc); v[1] = f2bs(a.y * sc); v[2] = f2bs(a.z * sc); v[3] = f2bs(a.w * sc);
    v[4] = f2bs(b.x * sc); v[5] = f2bs(b.y * sc); v[6] = f2bs(b.z * sc); v[7] = f2bs(b.w * sc);
    *(bf8_t*)dst = v;
}

__global__ __launch_bounds__(256) void prep_kernel(
    const float* __restrict__ x,
    const float* __restrict__ wq, const float* __restrict__ wk,
    const float* __restrict__ wv, const float* __restrict__ wo,
    const float* __restrict__ bq, const float* __restrict__ bk, const float* __restrict__ bv,
    __hip_bfloat16* __restrict__ xbf, __hip_bfloat16* __restrict__ wqkv,
    __hip_bfloat16* __restrict__ wobf, float* __restrict__ bqkv,
    long nx8, long nw8, long nb8)
{
    long u = (long)blockIdx.x * 256 + threadIdx.x;
    if (u < nx8) { cvt8(xbf + u * 8, x + u * 8, 1.0f); return; }
    u -= nx8;
    if (u < 3 * nw8) {
        long e = u * 8;
        long w1 = nw8 * 8;
        const float* src; float sc;
        if (e < w1)            { src = wq + e;           sc = QSCALE; }
        else if (e < 2 * w1)   { src = wk + (e - w1);    sc = 1.0f; }
        else                   { src = wv + (e - 2*w1);  sc = 1.0f; }
        cvt8(wqkv + e, src, sc);
        return;
    }
    u -= 3 * nw8;
    if (u < nw8) { cvt8(wobf + u * 8, wo + u * 8, 1.0f); return; }
    u -= nw8;
    if (u < nb8) {
        long e = u * 8;
        #pragma unroll
        for (int j = 0; j < 8; j++) {
            long i = e + j;
            float v;
            if (i < E_DIM)           v = bq[i] * QSCALE;
            else if (i < 2 * E_DIM)  v = bk[i - E_DIM];
            else                     v = bv[i - 2 * E_DIM];
            bqkv[i] = v;
        }
    }
}

// ---------------- m97-style NT GEMM (output proj): C = A*B^T + bias ----------------
template<bool BF16_OUT>
__global__ __launch_bounds__(256, 3) void gemm_nt(
    const __hip_bfloat16* __restrict__ A, const __hip_bfloat16* __restrict__ Bw,
    const float* __restrict__ bias, void* __restrict__ Cout,
    int M, int N, int K, int ldc)
{
    __shared__ __align__(16) __hip_bfloat16 As[128 * 32];
    __shared__ __align__(16) __hip_bfloat16 Bs[128 * 32];
    const int t = threadIdx.x;
    const int wv = t >> 6;
    const int ln = t & 63;
    const int m16 = ln & 15, q4 = ln >> 4;
    const int row0 = blockIdx.y * 128, col0 = blockIdx.x * 128;
    const int wm = (wv >> 1) * 64, wn = (wv & 1) * 64;

    f4_t acc[4][4] = {};

    for (int k0 = 0; k0 < K; k0 += 32) {
        #pragma unroll
        for (int i = 0; i < 2; i++) {
            int s = i * 256 + t;
            int r = s >> 2, c = s & 3;
            gl_lds16(A + (size_t)(row0 + r) * K + k0 + c * 8,
                     As + (size_t)(i * 256 + wv * 64) * 8);
        }
        #pragma unroll
        for (int i = 0; i < 2; i++) {
            int s = i * 256 + t;
            int r = s >> 2, c = s & 3;
            gl_lds16(Bw + (size_t)(col0 + r) * K + k0 + c * 8,
                     Bs + (size_t)(i * 256 + wv * 64) * 8);
        }
        __syncthreads();
        bf8_t af[4], bfr[4];
        #pragma unroll
        for (int mt = 0; mt < 4; mt++)
            af[mt] = *(const bf8_t*)&As[(wm + mt * 16 + m16) * 32 + q4 * 8];
        #pragma unroll
        for (int nt = 0; nt < 4; nt++)
            bfr[nt] = *(const bf8_t*)&Bs[(wn + nt * 16 + m16) * 32 + q4 * 8];
        #pragma unroll
        for (int mt = 0; mt < 4; mt++)
            #pragma unroll
            for (int nt = 0; nt < 4; nt++)
                acc[mt][nt] = mfma16x32(af[mt], bfr[nt], acc[mt][nt]);
        __syncthreads();
    }

    #pragma unroll
    for (int nt = 0; nt < 4; nt++) {
        int cg = col0 + wn + nt * 16 + m16;
        float bv = bias[cg];
        #pragma unroll
        for (int mt = 0; mt < 4; mt++) {
            #pragma unroll
            for (int r = 0; r < 4; r++) {
                int rg = row0 + wm + mt * 16 + q4 * 4 + r;
                float v = acc[mt][nt][r] + bv;
                if constexpr (BF16_OUT)
                    ((__hip_bfloat16*)Cout)[(long)rg * ldc + cg] = __float2bfloat16(v);
                else
                    ((float*)Cout)[(long)rg * ldc + cg] = v;
            }
        }
    }
}

// ---------------- 256x256 pipelined NT GEMM for QKV (T1+T2+T3/T4+T5 stack) --------
// V-column blocks (col0 >= 2E, block-uniform) write TRANSPOSED to vt[(cg-2E)*T + rg]
// as 8B bf4 stores (4 consecutive r = 4 consecutive tokens) -> vtrans_kernel deleted.
__global__ __launch_bounds__(512, 2) void gemm256(
    const __hip_bfloat16* __restrict__ A, const __hip_bfloat16* __restrict__ Bw,
    const float* __restrict__ bias, __hip_bfloat16* __restrict__ Cout,
    __hip_bfloat16* __restrict__ vtout, int Tdim,
    int M, int N, int K, int ldc)
{
    __shared__ __align__(16) __hip_bfloat16 As[2][256 * 64];  // 2 x 32 KB
    __shared__ __align__(16) __hip_bfloat16 Bs[2][256 * 64];  // 2 x 32 KB

    const int t = threadIdx.x;
    const int wv = t >> 6, ln = t & 63;
    const int m16 = ln & 15, q4 = ln >> 4;
    const int wr = wv >> 2, wc = wv & 3;   // 2 x 4 wave grid

    const int gx = N >> 8;
    const int nwg = gridDim.x;
    const int id = blockIdx.x;
    const int swz = ((nwg & 7) == 0) ? (id & 7) * (nwg >> 3) + (id >> 3) : id;  // T1 (bijective: nwg%8==0)
    const int col0 = (swz % gx) << 8;
    const int row0 = (swz / gx) << 8;

    const int NT = K >> 6;   // K-tiles of 64

    // stage one 256x64 tile: linear LDS dest (slot order), inverse-swizzled global src
    auto stage = [&](const __hip_bfloat16* src, __hip_bfloat16* dst) {
        #pragma unroll
        for (int i = 0; i < 4; i++) {
            int s = i * 512 + t;
            int r = s >> 3, c = (s & 7) ^ (r & 7);
            gl_lds16(src + (size_t)r * K + c * 8,
                     (char*)dst + (size_t)(i * 512 + wv * 64) * 16);
        }
    };

    // prologue: tiles 0 and 1
    stage(A  + (size_t)row0 * K,      &As[0][0]);
    stage(Bw + (size_t)col0 * K,      &Bs[0][0]);
    if (NT > 1) {
        stage(A  + (size_t)row0 * K + 64, &As[1][0]);
        stage(Bw + (size_t)col0 * K + 64, &Bs[1][0]);
        asm volatile("s_waitcnt vmcnt(8)" ::: "memory");   // tile 0 landed; tile 1 in flight
    } else {
        asm volatile("s_waitcnt vmcnt(0)" ::: "memory");
    }
    __builtin_amdgcn_s_barrier();

    f4_t acc[8][4] = {};

    for (int kt = 0; kt < NT; kt++) {
        const __hip_bfloat16* Ab = &As[kt & 1][0];
        const __hip_bfloat16* Bb = &Bs[kt & 1][0];

        auto lda = [&](const __hip_bfloat16* base, int r, int kc) {
            return *(const bf8_t*)&base[r * 64 + ((((kc << 2) | q4) ^ (r & 7)) << 3)];
        };

        bf8_t afr[4][2], bf0[2][2], bf1[2][2];
        // Q(mh0,nh0): af half 0 (8 reads) + bf half 0 (4 reads)
        #pragma unroll
        for (int mt = 0; mt < 4; mt++)
            #pragma unroll
            for (int kc = 0; kc < 2; kc++)
                afr[mt][kc] = lda(Ab, wr * 128 + mt * 16 + m16, kc);
        #pragma unroll
        for (int nt = 0; nt < 2; nt++)
            #pragma unroll
            for (int kc = 0; kc < 2; kc++)
                bf0[nt][kc] = lda(Bb, wc * 64 + nt * 16 + m16, kc);

        __builtin_amdgcn_s_setprio(1);
        #pragma unroll
        for (int mt = 0; mt < 4; mt++)
            #pragma unroll
            for (int nt = 0; nt < 2; nt++)
                #pragma unroll
                for (int kc = 0; kc < 2; kc++)
                    acc[mt][nt] = mfma16x32(afr[mt][kc], bf0[nt][kc], acc[mt][nt]);
        __builtin_amdgcn_s_setprio(0);

        // Q(mh0,nh1): new bf half 1 (4 reads)
        #pragma unroll
        for (int nt = 0; nt < 2; nt++)
            #pragma unroll
            for (int kc = 0; kc < 2; kc++)
                bf1[nt][kc] = lda(Bb, wc * 64 + (2 + nt) * 16 + m16, kc);

        __builtin_amdgcn_s_setprio(1);
        #pragma unroll
        for (int mt = 0; mt < 4; mt++)
            #pragma unroll
            for (int nt = 0; nt < 2; nt++)
                #pragma unroll
                for (int kc = 0; kc < 2; kc++)
                    acc[mt][2 + nt] = mfma16x32(afr[mt][kc], bf1[nt][kc], acc[mt][2 + nt]);
        __builtin_amdgcn_s_setprio(0);

        // Q(mh1,nh1): new af half 1 (8 reads)
        #pragma unroll
        for (int mt = 0; mt < 4; mt++)
            #pragma unroll
            for (int kc = 0; kc < 2; kc++)
                afr[mt][kc] = lda(Ab, wr * 128 + (4 + mt) * 16 + m16, kc);

        __builtin_amdgcn_s_setprio(1);
        #pragma unroll
        for (int mt = 0; mt < 4; mt++)
            #pragma unroll
            for (int nt = 0; nt < 2; nt++)
                #pragma unroll
                for (int kc = 0; kc < 2; kc++)
                    acc[4 + mt][2 + nt] = mfma16x32(afr[mt][kc], bf1[nt][kc], acc[4 + mt][2 + nt]);
        __builtin_amdgcn_s_setprio(0);

        // Q(mh1,nh0): bf half 0 still live
        __builtin_amdgcn_s_setprio(1);
        #pragma unroll
        for (int mt = 0; mt < 4; mt++)
            #pragma unroll
            for (int nt = 0; nt < 2; nt++)
                #pragma unroll
                for (int kc = 0; kc < 2; kc++)
                    acc[4 + mt][nt] = mfma16x32(afr[mt][kc], bf0[nt][kc], acc[4 + mt][nt]);
        __builtin_amdgcn_s_setprio(0);

        // all reads of slot kt&1 done (per-wave lgkmcnt before MFMA; barrier -> all waves)
        asm volatile("s_waitcnt lgkmcnt(0)" ::: "memory");
        __builtin_amdgcn_s_barrier();

        if (kt + 2 < NT) {   // restage the just-freed slot for tile kt+2
            stage(A  + (size_t)row0 * K + (size_t)(kt + 2) * 64, &As[kt & 1][0]);
            stage(Bw + (size_t)col0 * K + (size_t)(kt + 2) * 64, &Bs[kt & 1][0]);
        }
        if (kt + 1 < NT) {
            if (kt + 2 < NT)
                asm volatile("s_waitcnt vmcnt(8)" ::: "memory");  // tile kt+1 landed; kt+2 in flight
            else
                asm volatile("s_waitcnt vmcnt(0)" ::: "memory");  // drain last tile
            __builtin_amdgcn_s_barrier();
        }
    }

    if (col0 >= 2 * E_DIM) {
        // V block: write transposed into vt, 8B bf4 per (mt,nt) (4 consecutive tokens)
        #pragma unroll
        for (int nt = 0; nt < 4; nt++) {
            int cg = col0 + wc * 64 + nt * 16 + m16;
            float bval = bias[cg];
            int vrow = cg - 2 * E_DIM;
            #pragma unroll
            for (int mt = 0; mt < 8; mt++) {
                int rg0 = row0 + wr * 128 + mt * 16 + q4 * 4;
                f4_t vv;
                #pragma unroll
                for (int r = 0; r < 4; r++) vv[r] = acc[mt][nt][r] + bval;
                *(bf4_t*)&vtout[(long)vrow * Tdim + rg0] = pk4(vv);
            }
        }
    } else {
        #pragma unroll
        for (int nt = 0; nt < 4; nt++) {
            int cg = col0 + wc * 64 + nt * 16 + m16;
            float bval = bias[cg];
            #pragma unroll
            for (int mt = 0; mt < 8; mt++) {
                #pragma unroll
                for (int r = 0; r < 4; r++) {
                    int rg = row0 + wr * 128 + mt * 16 + q4 * 4 + r;
                    Cout[(long)rg * ldc + cg] = __float2bfloat16(acc[mt][nt][r] + bval);
                }
            }
        }
    }
}

// ---------------- RoPE (in place on q,k sections of qkv) ----------------
__global__ __launch_bounds__(256) void rope_kernel(
    __hip_bfloat16* __restrict__ qkv, const int* __restrict__ cu, int B, int T)
{
    long idx = (long)blockIdx.x * 256 + threadIdx.x;
    int i = idx & 31;
    long r = idx >> 5;
    int h = (int)(r % NHEADS);
    int tok = (int)(r / NHEADS);
    if (tok >= T) return;
    int pos = tok;
    for (int b = 1; b <= B; b++) if (tok >= cu[b]) pos = tok - cu[b];
    float f = (float)pos * exp2f(-(float)i * 0.41524100558003436f);
    float s, c;
    sincosf(f, &s, &c);
    long base = (long)tok * QKV_LD + h * HDIM + i;
    {
        float q1 = __bfloat162float(qkv[base]);
        float q2 = __bfloat162float(qkv[base + 32]);
        qkv[base]      = __float2bfloat16(q1 * c - q2 * s);
        qkv[base + 32] = __float2bfloat16(q2 * c + q1 * s);
    }
    {
        long kb = base + E_DIM;
        float k1 = __bfloat162float(qkv[kb]);
        float k2 = __bfloat162float(qkv[kb + 32]);
        qkv[kb]      = __float2bfloat16(k1 * c - k2 * s);
        qkv[kb + 32] = __float2bfloat16(k2 * c + k1 * s);
    }
}

// ---------------- flash attention: round-5 = + softmax||PV pipeline (T15) ----------------
// Round-4 counters: VALUBusy 59 / MfmaUtil 24 / HBM 8% -> wave-issue-bound on the serial
// QK -> softmax -> PV chain. This round holds P(i-1) packed in regs (bp, +32 VGPR, free:
// occupancy is LDS-bound) and runs PV(i-1) adjacent to softmax(i) so MFMA and VALU pipes
// overlap. V triple-buffered (PV(i-1) reads V[(i-1)%3] while staging writes V[(i+1)%3]).
// P pack via v_cvt_pk_bf16_f32 (T12): 32 instr/tile instead of 64 scalar RNE converts.
__global__ __launch_bounds__(256, 2) void attn_kernel(
    const __hip_bfloat16* __restrict__ qkv, const __hip_bfloat16* __restrict__ vt,
    const int* __restrict__ cu, __hip_bfloat16* __restrict__ obuf, int B, int T)
{
    __shared__ __align__(16) __hip_bfloat16 Ks[2][128 * 64];  // [key][d] swizzled, 2x16 KB
    __shared__ __align__(16) __hip_bfloat16 Vs[3][64 * 128];  // [d][key] swizzled, 3x16 KB

    int idx = blockIdx.x;
    int h = idx % NHEADS;
    int gt = idx / NHEADS;
    int b = 0, l = 0, seq0 = 0;
    for (; b < B; ++b) {
        seq0 = cu[b];
        l = cu[b + 1] - seq0;
        int ntile = (l + 127) >> 7;
        if (gt < ntile) break;
        gt -= ntile;
    }
    if (b == B) return;
    int q0 = gt * 128;
    const int NT = (l + 127) >> 7;

    const int t = threadIdx.x;
    const int wv = t >> 6, ln = t & 63;
    const int m16 = ln & 15, q4 = ln >> 4;

    // K: slot s2 -> row s2>>3, chunk (s2&7)^(row&7); V: row s2>>4, chunk (s2&15)^(row&15)
    auto stage_full = [&](int kv0n, int kb, int vb) {
        #pragma unroll
        for (int i = 0; i < 4; i++) {
            int s2 = i * 256 + t;
            int key = s2 >> 3, cg = (s2 & 7) ^ (key & 7);
            gl_lds16(qkv + (long)(seq0 + kv0n + key) * QKV_LD + E_DIM + h * HDIM + cg * 8,
                     (char*)&Ks[kb][0] + (size_t)(i * 256 + wv * 64) * 16);
        }
        #pragma unroll
        for (int i = 0; i < 4; i++) {
            int s2 = i * 256 + t;
            int d = s2 >> 4, cg = (s2 & 15) ^ (d & 15);
            gl_lds16(vt + (long)(h * HDIM + d) * T + seq0 + kv0n + cg * 8,
                     (char*)&Vs[vb][0] + (size_t)(i * 256 + wv * 64) * 16);
        }
    };
    auto stage_tail = [&](int kv0n, int kb, int vb) {   // dead in this workload (l % 128 == 0)
        #pragma unroll
        for (int i = 0; i < 4; i++) {
            int s2 = i * 256 + t;
            int key = s2 >> 3, c = s2 & 7;
            bf8_t v = (bf8_t)0;
            if (kv0n + key < l)
                v = *(const bf8_t*)(qkv + (long)(seq0 + kv0n + key) * QKV_LD + E_DIM + h * HDIM + c * 8);
            *(bf8_t*)&Ks[kb][key * 64 + (c ^ (key & 7)) * 8] = v;
        }
        #pragma unroll
        for (int i = 0; i < 4; i++) {
            int s2 = i * 256 + t;
            int d = s2 >> 4, c = s2 & 15;
            bf8_t v = (bf8_t)0;
            int tb = kv0n + c * 8;
            #pragma unroll
            for (int u = 0; u < 8; u++)
                if (tb + u < l)
                    v[u] = *(const short*)&vt[(long)(h * HDIM + d) * T + seq0 + tb + u];
            *(bf8_t*)&Vs[vb][d * 128 + (c ^ (d & 15)) * 8] = v;
        }
    };

    // prologue: issue staging of tile 0 first, then load Q while it flies
    if (128 <= l) stage_full(0, 0, 0); else stage_tail(0, 0, 0);

    // Q B-frags in registers: bq[nt][kc] = B[k=kc*32+q4*8+j][n=m16]
    bf8_t bq[2][2];
    #pragma unroll
    for (int nt = 0; nt < 2; nt++) {
        int qrow = q0 + wv * 32 + nt * 16 + m16;
        #pragma unroll
        for (int kc = 0; kc < 2; kc++) {
            bf8_t v = (bf8_t)0;
            if (qrow < l)
                v = *(const bf8_t*)(qkv + (long)(seq0 + qrow) * QKV_LD + h * HDIM + kc * 32 + q4 * 8);
            bq[nt][kc] = v;
        }
    }

    f4_t oacc[2][4] = {};
    float m_s[2] = {-1e30f, -1e30f};
    float l_s[2] = {0.0f, 0.0f};
    bf4_t bp[8][2];          // packed P of the PREVIOUS tile
    int vprev = 0;

    const int ksw0 = (q4 ^ (m16 & 7)) * 8;        // slot of global chunk q4
    const int ksw1 = ((4 + q4) ^ (m16 & 7)) * 8;  // slot of global chunk 4+q4

    auto do_pv = [&](const __hip_bfloat16* Vb) {
        __builtin_amdgcn_s_setprio(1);
        #pragma unroll
        for (int mt = 0; mt < 8; mt++) {
            const int vsw = ((mt * 2 + (q4 >> 1)) ^ m16) * 8 + (q4 & 1) * 4;
            #pragma unroll
            for (int dt = 0; dt < 4; dt++) {
                bf4_t av = *(const bf4_t*)&Vb[(dt * 16 + m16) * 128 + vsw];
                #pragma unroll
                for (int nt = 0; nt < 2; nt++)
                    oacc[nt][dt] = mfma16x16(av, bp[mt][nt], oacc[nt][dt]);
            }
        }
        __builtin_amdgcn_s_setprio(0);
    };

    asm volatile("s_waitcnt vmcnt(0) lgkmcnt(0)" ::: "memory");
    __builtin_amdgcn_s_barrier();

    for (int it = 0; it < NT; ++it) {
        const int kv0 = it << 7;
        const bool full = (kv0 + 128 <= l);
        if (it + 1 < NT) {                       // issue next tile's loads NOW
            int kvn = kv0 + 128;
            if (kvn + 128 <= l) stage_full(kvn, (it + 1) & 1, (it + 1) % 3);
            else stage_tail(kvn, (it + 1) & 1, (it + 1) % 3);
        }
        const __hip_bfloat16* Kb = Ks[it & 1];

        // S^T = K.Q^T : S[nt][mt] holds S^T[key=mt*16+q4*4+r][qrow=m16]
        f4_t S[2][8];
        __builtin_amdgcn_s_setprio(1);
        #pragma unroll
        for (int mt = 0; mt < 8; mt++) {
            const __hip_bfloat16* krow = &Kb[(mt * 16 + m16) * 64];
            bf8_t ak0 = *(const bf8_t*)(krow + ksw0);
            bf8_t ak1 = *(const bf8_t*)(krow + ksw1);
            #pragma unroll
            for (int nt = 0; nt < 2; nt++) {
                f4_t a = {};
                a = mfma16x32(ak0, bq[nt][0], a);
                a = mfma16x32(ak1, bq[nt][1], a);
                S[nt][mt] = a;
            }
        }
        __builtin_amdgcn_s_setprio(0);

        if (!full) {
            #pragma unroll
            for (int mt = 0; mt < 8; mt++) {
                #pragma unroll
                for (int r = 0; r < 4; r++) {
                    bool valid = (kv0 + mt * 16 + q4 * 4 + r) < l;
                    #pragma unroll
                    for (int nt = 0; nt < 2; nt++)
                        if (!valid) S[nt][mt][r] = -1e30f;
                }
            }
        }

        // PV of PREVIOUS tile — independent of softmax(it) below except the deferred
        // oacc rescale (register dep orders it after these MFMAs automatically).
        if (it > 0) do_pv(Vs[vprev]);

        // online softmax (base-2 domain; log2e folded into Wq/bq) + defer-max (THR=8)
        #pragma unroll
        for (int nt = 0; nt < 2; nt++) {
            float mx = -1e30f;
            #pragma unroll
            for (int mt = 0; mt < 8; mt++)
                #pragma unroll
                for (int r = 0; r < 4; r++)
                    mx = fmaxf(mx, S[nt][mt][r]);
            mx = fmaxf(mx, __shfl_xor(mx, 16));
            mx = fmaxf(mx, __shfl_xor(mx, 32));
            if (!__all(mx - m_s[nt] <= 8.0f)) {
                float mn = fmaxf(m_s[nt], mx);
                float al = exp2f(m_s[nt] - mn);
                m_s[nt] = mn;
                l_s[nt] *= al;
                #pragma unroll
                for (int dt = 0; dt < 4; dt++)
                    #pragma unroll
                    for (int r = 0; r < 4; r++)
                        oacc[nt][dt][r] *= al;
            }
            float mcur = m_s[nt];
            float ls = 0.0f;
            #pragma unroll
            for (int mt = 0; mt < 8; mt++) {
                #pragma unroll
                for (int r = 0; r < 4; r++) {
                    float p = exp2f(S[nt][mt][r] - mcur);
                    ls += p;
                    S[nt][mt][r] = p;
                }
            }
            l_s[nt] += ls;
        }

        // pack P(it) for next iteration's PV (hw packed converts)
        #pragma unroll
        for (int mt = 0; mt < 8; mt++)
            #pragma unroll
            for (int nt = 0; nt < 2; nt++)
                bp[mt][nt] = pk4(S[nt][mt]);
        vprev = it % 3;

        if (it + 1 < NT) {
            asm volatile("s_waitcnt vmcnt(0) lgkmcnt(0)" ::: "memory");
            __builtin_amdgcn_s_barrier();
        }
    }

    // drain: PV of the last tile
    do_pv(Vs[vprev]);

    // finalize
    #pragma unroll
    for (int nt = 0; nt < 2; nt++) {
        float ls = l_s[nt];
        ls += __shfl_xor(ls, 16);
        ls += __shfl_xor(ls, 32);
        float inv = 1.0f / ls;
        int qrow = q0 + wv * 32 + nt * 16 + m16;
        if (qrow < l) {
            #pragma unroll
            for (int dt = 0; dt < 4; dt++) {
                f4_t o;
                #pragma unroll
                for (int r = 0; r < 4; r++)
                    o[r] = oacc[nt][dt][r] * inv;
                *(bf4_t*)&obuf[(long)(seq0 + qrow) * E_DIM + h * HDIM + dt * 16 + q4 * 4] = pk4(o);
            }
        }
    }
}

// ---------------- launch ----------------
extern "C" void kernel_launch(void* const* d_in, const int* in_sizes, int n_in,
                              void* d_out, int out_size, void* d_ws, size_t ws_size,
                              hipStream_t stream) {
    const int E = E_DIM;
    const int T = in_sizes[0] / E;      // 8192
    const int B = in_sizes[1] - 1;      // 8

    const float* x  = (const float*)d_in[0];
    const int*   cu = (const int*)d_in[1];
    const float* Wq = (const float*)d_in[3];
    const float* bq = (const float*)d_in[4];
    const float* Wk = (const float*)d_in[5];
    const float* bk = (const float*)d_in[6];
    const float* Wv = (const float*)d_in[7];
    const float* bv = (const float*)d_in[8];
    const float* Wo = (const float*)d_in[9];
    const float* bo = (const float*)d_in[10];

    char* ws = (char*)d_ws;
    size_t off = 0;
    auto alloc = [&](size_t bytes) -> void* {
        void* p = ws + off;
        off = (off + bytes + 255) & ~(size_t)255;
        return p;
    };
    __hip_bfloat16* xbf   = (__hip_bfloat16*)alloc((size_t)T * E * 2);
    __hip_bfloat16* wqkv  = (__hip_bfloat16*)alloc((size_t)3 * E * E * 2);
    __hip_bfloat16* wobf  = (__hip_bfloat16*)alloc((size_t)E * E * 2);
    float*          bqkv  = (float*)alloc((size_t)3 * E * 4);
    __hip_bfloat16* qkvb  = (__hip_bfloat16*)alloc((size_t)T * 3 * E * 2);
    __hip_bfloat16* vt    = (__hip_bfloat16*)alloc((size_t)E * T * 2);
    __hip_bfloat16* obuf  = xbf;  // alias: x_bf dead after QKV GEMM

    long nx8 = (long)T * E / 8;
    long nw8 = (long)E * E / 8;
    long nb8 = (long)3 * E / 8;
    long total = nx8 + 4 * nw8 + nb8;
    int pblocks = (int)((total + 255) / 256);
    prep_kernel<<<pblocks, 256, 0, stream>>>(x, Wq, Wk, Wv, Wo, bq, bk, bv,
                                             xbf, wqkv, wobf, bqkv, nx8, nw8, nb8);

    // QKV projection: 256^2-tile pipelined GEMM; V columns written transposed to vt
    gemm256<<<(T / 256) * (3 * E / 256), 512, 0, stream>>>(
        xbf, wqkv, bqkv, qkvb, vt, T, T, 3 * E, E, 3 * E);

    rope_kernel<<<(int)(((long)T * NHEADS * 32) / 256), 256, 0, stream>>>(qkvb, cu, B, T);

    // 128-row q-tiles: upper bound on sum of per-seq ceil(l/128)
    int qtiles_ub = T / 128 + B;
    attn_kernel<<<qtiles_ub * NHEADS, 256, 0, stream>>>(qkvb, vt, cu, obuf, B, T);

    // output projection: N=1280 -> only 160 blocks at 256^2; keep 128^2 (640 blocks)
    gemm_nt<false><<<dim3(E / 128, T / 128), 256, 0, stream>>>(
        obuf, wobf, bo, d_out, T, E, E, E);
}

// Round 5
// 384.378 us; speedup vs baseline: 1.3278x; 1.0039x over previous
//
#include <hip/hip_runtime.h>
#include <hip/hip_bf16.h>
#include <cstdint>

#define E_DIM   1280
#define NHEADS  20
#define HDIM    64
#define QKV_LD  3840   // 3*E

typedef __attribute__((ext_vector_type(8))) short bf8_t;   // 8 bf16 (4 VGPRs)
typedef __attribute__((ext_vector_type(4))) short bf4_t;   // 4 bf16 (2 VGPRs)
typedef __attribute__((ext_vector_type(4))) float f4_t;    // MFMA accumulator

__device__ __forceinline__ short f2bs(float f) {
    union { __hip_bfloat16 h; short s; } u;
    u.h = __float2bfloat16(f);
    return u.s;
}

// hardware packed f32x2 -> bf16x2 (RNE), T12 recipe: no builtin on gfx950
__device__ __forceinline__ bf4_t pk4(f4_t s) {
    union { bf4_t v; uint32_t u[2]; } r;
    asm("v_cvt_pk_bf16_f32 %0, %1, %2" : "=v"(r.u[0]) : "v"(s[0]), "v"(s[1]));
    asm("v_cvt_pk_bf16_f32 %0, %1, %2" : "=v"(r.u[1]) : "v"(s[2]), "v"(s[3]));
    return r.v;
}

__device__ __forceinline__ f4_t mfma16x32(bf8_t a, bf8_t b, f4_t c) {
    return __builtin_amdgcn_mfma_f32_16x16x32_bf16(a, b, c, 0, 0, 0);
}
__device__ __forceinline__ f4_t mfma16x16(bf4_t a, bf4_t b, f4_t c) {
    return __builtin_amdgcn_mfma_f32_16x16x16bf16_1k(a, b, c, 0, 0, 0);
}

// async global->LDS, 16B per lane. LDS dest is wave-uniform base + lane*16.
__device__ __forceinline__ void gl_lds16(const void* g, void* l) {
    auto gp = reinterpret_cast<__attribute__((address_space(1))) unsigned int*>(
        reinterpret_cast<uintptr_t>(g));
    auto lp = reinterpret_cast<__attribute__((address_space(3))) unsigned int*>(
        reinterpret_cast<uintptr_t>(l));
    __builtin_amdgcn_global_load_lds(gp, lp, 16, 0, 0);
}

// ---------------- prep: casts + weight concat + bias concat ----------------
// Wq/bq scale = d^-0.5 * log2(e): softmax computed in base-2 domain (exp2f).
#define QSCALE 0.18033688011112042f

__device__ __forceinline__ void cvt8(__hip_bfloat16* dst, const float* src, float sc) {
    float4 a = *(const float4*)src;
    float4 b = *(const float4*)(src + 4);
    bf8_t v;
    v[0] = f2bs(a.x * sc); v[1] = f2bs(a.y * sc); v[2] = f2bs(a.z * sc); v[3] = f2bs(a.w * sc);
    v[4] = f2bs(b.x * sc); v[5] = f2bs(b.y * sc); v[6] = f2bs(b.z * sc); v[7] = f2bs(b.w * sc);
    *(bf8_t*)dst = v;
}

__global__ __launch_bounds__(256) void prep_kernel(
    const float* __restrict__ x,
    const float* __restrict__ wq, const float* __restrict__ wk,
    const float* __restrict__ wv, const float* __restrict__ wo,
    const float* __restrict__ bq, const float* __restrict__ bk, const float* __restrict__ bv,
    __hip_bfloat16* __restrict__ xbf, __hip_bfloat16* __restrict__ wqkv,
    __hip_bfloat16* __restrict__ wobf, float* __restrict__ bqkv,
    long nx8, long nw8, long nb8)
{
    long u = (long)blockIdx.x * 256 + threadIdx.x;
    if (u < nx8) { cvt8(xbf + u * 8, x + u * 8, 1.0f); return; }
    u -= nx8;
    if (u < 3 * nw8) {
        long e = u * 8;
        long w1 = nw8 * 8;
        const float* src; float sc;
        if (e < w1)            { src = wq + e;           sc = QSCALE; }
        else if (e < 2 * w1)   { src = wk + (e - w1);    sc = 1.0f; }
        else                   { src = wv + (e - 2*w1);  sc = 1.0f; }
        cvt8(wqkv + e, src, sc);
        return;
    }
    u -= 3 * nw8;
    if (u < nw8) { cvt8(wobf + u * 8, wo + u * 8, 1.0f); return; }
    u -= nw8;
    if (u < nb8) {
        long e = u * 8;
        #pragma unroll
        for (int j = 0; j < 8; j++) {
            long i = e + j;
            float v;
            if (i < E_DIM)           v = bq[i] * QSCALE;
            else if (i < 2 * E_DIM)  v = bk[i - E_DIM];
            else                     v = bv[i - 2 * E_DIM];
            bqkv[i] = v;
        }
    }
}

// ---------------- m97-style NT GEMM (output proj): C = A*B^T + bias ----------------
template<bool BF16_OUT>
__global__ __launch_bounds__(256, 3) void gemm_nt(
    const __hip_bfloat16* __restrict__ A, const __hip_bfloat16* __restrict__ Bw,
    const float* __restrict__ bias, void* __restrict__ Cout,
    int M, int N, int K, int ldc)
{
    __shared__ __align__(16) __hip_bfloat16 As[128 * 32];
    __shared__ __align__(16) __hip_bfloat16 Bs[128 * 32];
    const int t = threadIdx.x;
    const int wv = t >> 6;
    const int ln = t & 63;
    const int m16 = ln & 15, q4 = ln >> 4;
    const int row0 = blockIdx.y * 128, col0 = blockIdx.x * 128;
    const int wm = (wv >> 1) * 64, wn = (wv & 1) * 64;

    f4_t acc[4][4] = {};

    for (int k0 = 0; k0 < K; k0 += 32) {
        #pragma unroll
        for (int i = 0; i < 2; i++) {
            int s = i * 256 + t;
            int r = s >> 2, c = s & 3;
            gl_lds16(A + (size_t)(row0 + r) * K + k0 + c * 8,
                     As + (size_t)(i * 256 + wv * 64) * 8);
        }
        #pragma unroll
        for (int i = 0; i < 2; i++) {
            int s = i * 256 + t;
            int r = s >> 2, c = s & 3;
            gl_lds16(Bw + (size_t)(col0 + r) * K + k0 + c * 8,
                     Bs + (size_t)(i * 256 + wv * 64) * 8);
        }
        __syncthreads();
        bf8_t af[4], bfr[4];
        #pragma unroll
        for (int mt = 0; mt < 4; mt++)
            af[mt] = *(const bf8_t*)&As[(wm + mt * 16 + m16) * 32 + q4 * 8];
        #pragma unroll
        for (int nt = 0; nt < 4; nt++)
            bfr[nt] = *(const bf8_t*)&Bs[(wn + nt * 16 + m16) * 32 + q4 * 8];
        #pragma unroll
        for (int mt = 0; mt < 4; mt++)
            #pragma unroll
            for (int nt = 0; nt < 4; nt++)
                acc[mt][nt] = mfma16x32(af[mt], bfr[nt], acc[mt][nt]);
        __syncthreads();
    }

    #pragma unroll
    for (int nt = 0; nt < 4; nt++) {
        int cg = col0 + wn + nt * 16 + m16;
        float bv = bias[cg];
        #pragma unroll
        for (int mt = 0; mt < 4; mt++) {
            #pragma unroll
            for (int r = 0; r < 4; r++) {
                int rg = row0 + wm + mt * 16 + q4 * 4 + r;
                float v = acc[mt][nt][r] + bv;
                if constexpr (BF16_OUT)
                    ((__hip_bfloat16*)Cout)[(long)rg * ldc + cg] = __float2bfloat16(v);
                else
                    ((float*)Cout)[(long)rg * ldc + cg] = v;
            }
        }
    }
}

// ---------------- 256x256 pipelined NT GEMM for QKV (T1+T2+T3/T4+T5 stack) --------
// V-column blocks (col0 >= 2E, block-uniform) write TRANSPOSED to vt[(cg-2E)*T + rg]
// as 8B bf4 stores (4 consecutive r = 4 consecutive tokens) -> vtrans_kernel deleted.
__global__ __launch_bounds__(512, 2) void gemm256(
    const __hip_bfloat16* __restrict__ A, const __hip_bfloat16* __restrict__ Bw,
    const float* __restrict__ bias, __hip_bfloat16* __restrict__ Cout,
    __hip_bfloat16* __restrict__ vtout, int Tdim,
    int M, int N, int K, int ldc)
{
    __shared__ __align__(16) __hip_bfloat16 As[2][256 * 64];  // 2 x 32 KB
    __shared__ __align__(16) __hip_bfloat16 Bs[2][256 * 64];  // 2 x 32 KB

    const int t = threadIdx.x;
    const int wv = t >> 6, ln = t & 63;
    const int m16 = ln & 15, q4 = ln >> 4;
    const int wr = wv >> 2, wc = wv & 3;   // 2 x 4 wave grid

    const int gx = N >> 8;
    const int nwg = gridDim.x;
    const int id = blockIdx.x;
    const int swz = ((nwg & 7) == 0) ? (id & 7) * (nwg >> 3) + (id >> 3) : id;  // T1 (bijective: nwg%8==0)
    const int col0 = (swz % gx) << 8;
    const int row0 = (swz / gx) << 8;

    const int NT = K >> 6;   // K-tiles of 64

    // stage one 256x64 tile: linear LDS dest (slot order), inverse-swizzled global src
    auto stage = [&](const __hip_bfloat16* src, __hip_bfloat16* dst) {
        #pragma unroll
        for (int i = 0; i < 4; i++) {
            int s = i * 512 + t;
            int r = s >> 3, c = (s & 7) ^ (r & 7);
            gl_lds16(src + (size_t)r * K + c * 8,
                     (char*)dst + (size_t)(i * 512 + wv * 64) * 16);
        }
    };

    // prologue: tiles 0 and 1
    stage(A  + (size_t)row0 * K,      &As[0][0]);
    stage(Bw + (size_t)col0 * K,      &Bs[0][0]);
    if (NT > 1) {
        stage(A  + (size_t)row0 * K + 64, &As[1][0]);
        stage(Bw + (size_t)col0 * K + 64, &Bs[1][0]);
        asm volatile("s_waitcnt vmcnt(8)" ::: "memory");   // tile 0 landed; tile 1 in flight
    } else {
        asm volatile("s_waitcnt vmcnt(0)" ::: "memory");
    }
    __builtin_amdgcn_s_barrier();

    f4_t acc[8][4] = {};

    for (int kt = 0; kt < NT; kt++) {
        const __hip_bfloat16* Ab = &As[kt & 1][0];
        const __hip_bfloat16* Bb = &Bs[kt & 1][0];

        auto lda = [&](const __hip_bfloat16* base, int r, int kc) {
            return *(const bf8_t*)&base[r * 64 + ((((kc << 2) | q4) ^ (r & 7)) << 3)];
        };

        bf8_t afr[4][2], bf0[2][2], bf1[2][2];
        // Q(mh0,nh0): af half 0 (8 reads) + bf half 0 (4 reads)
        #pragma unroll
        for (int mt = 0; mt < 4; mt++)
            #pragma unroll
            for (int kc = 0; kc < 2; kc++)
                afr[mt][kc] = lda(Ab, wr * 128 + mt * 16 + m16, kc);
        #pragma unroll
        for (int nt = 0; nt < 2; nt++)
            #pragma unroll
            for (int kc = 0; kc < 2; kc++)
                bf0[nt][kc] = lda(Bb, wc * 64 + nt * 16 + m16, kc);

        __builtin_amdgcn_s_setprio(1);
        #pragma unroll
        for (int mt = 0; mt < 4; mt++)
            #pragma unroll
            for (int nt = 0; nt < 2; nt++)
                #pragma unroll
                for (int kc = 0; kc < 2; kc++)
                    acc[mt][nt] = mfma16x32(afr[mt][kc], bf0[nt][kc], acc[mt][nt]);
        __builtin_amdgcn_s_setprio(0);

        // Q(mh0,nh1): new bf half 1 (4 reads)
        #pragma unroll
        for (int nt = 0; nt < 2; nt++)
            #pragma unroll
            for (int kc = 0; kc < 2; kc++)
                bf1[nt][kc] = lda(Bb, wc * 64 + (2 + nt) * 16 + m16, kc);

        __builtin_amdgcn_s_setprio(1);
        #pragma unroll
        for (int mt = 0; mt < 4; mt++)
            #pragma unroll
            for (int nt = 0; nt < 2; nt++)
                #pragma unroll
                for (int kc = 0; kc < 2; kc++)
                    acc[mt][2 + nt] = mfma16x32(afr[mt][kc], bf1[nt][kc], acc[mt][2 + nt]);
        __builtin_amdgcn_s_setprio(0);

        // Q(mh1,nh1): new af half 1 (8 reads)
        #pragma unroll
        for (int mt = 0; mt < 4; mt++)
            #pragma unroll
            for (int kc = 0; kc < 2; kc++)
                afr[mt][kc] = lda(Ab, wr * 128 + (4 + mt) * 16 + m16, kc);

        __builtin_amdgcn_s_setprio(1);
        #pragma unroll
        for (int mt = 0; mt < 4; mt++)
            #pragma unroll
            for (int nt = 0; nt < 2; nt++)
                #pragma unroll
                for (int kc = 0; kc < 2; kc++)
                    acc[4 + mt][2 + nt] = mfma16x32(afr[mt][kc], bf1[nt][kc], acc[4 + mt][2 + nt]);
        __builtin_amdgcn_s_setprio(0);

        // Q(mh1,nh0): bf half 0 still live
        __builtin_amdgcn_s_setprio(1);
        #pragma unroll
        for (int mt = 0; mt < 4; mt++)
            #pragma unroll
            for (int nt = 0; nt < 2; nt++)
                #pragma unroll
                for (int kc = 0; kc < 2; kc++)
                    acc[4 + mt][nt] = mfma16x32(afr[mt][kc], bf0[nt][kc], acc[4 + mt][nt]);
        __builtin_amdgcn_s_setprio(0);

        // all reads of slot kt&1 done (per-wave lgkmcnt before MFMA; barrier -> all waves)
        asm volatile("s_waitcnt lgkmcnt(0)" ::: "memory");
        __builtin_amdgcn_s_barrier();

        if (kt + 2 < NT) {   // restage the just-freed slot for tile kt+2
            stage(A  + (size_t)row0 * K + (size_t)(kt + 2) * 64, &As[kt & 1][0]);
            stage(Bw + (size_t)col0 * K + (size_t)(kt + 2) * 64, &Bs[kt & 1][0]);
        }
        if (kt + 1 < NT) {
            if (kt + 2 < NT)
                asm volatile("s_waitcnt vmcnt(8)" ::: "memory");  // tile kt+1 landed; kt+2 in flight
            else
                asm volatile("s_waitcnt vmcnt(0)" ::: "memory");  // drain last tile
            __builtin_amdgcn_s_barrier();
        }
    }

    if (col0 >= 2 * E_DIM) {
        // V block: write transposed into vt, 8B bf4 per (mt,nt) (4 consecutive tokens)
        #pragma unroll
        for (int nt = 0; nt < 4; nt++) {
            int cg = col0 + wc * 64 + nt * 16 + m16;
            float bval = bias[cg];
            int vrow = cg - 2 * E_DIM;
            #pragma unroll
            for (int mt = 0; mt < 8; mt++) {
                int rg0 = row0 + wr * 128 + mt * 16 + q4 * 4;
                f4_t vv;
                #pragma unroll
                for (int r = 0; r < 4; r++) vv[r] = acc[mt][nt][r] + bval;
                *(bf4_t*)&vtout[(long)vrow * Tdim + rg0] = pk4(vv);
            }
        }
    } else {
        #pragma unroll
        for (int nt = 0; nt < 4; nt++) {
            int cg = col0 + wc * 64 + nt * 16 + m16;
            float bval = bias[cg];
            #pragma unroll
            for (int mt = 0; mt < 8; mt++) {
                #pragma unroll
                for (int r = 0; r < 4; r++) {
                    int rg = row0 + wr * 128 + mt * 16 + q4 * 4 + r;
                    Cout[(long)rg * ldc + cg] = __float2bfloat16(acc[mt][nt][r] + bval);
                }
            }
        }
    }
}

// ---------------- RoPE (in place on q,k sections of qkv) ----------------
__global__ __launch_bounds__(256) void rope_kernel(
    __hip_bfloat16* __restrict__ qkv, const int* __restrict__ cu, int B, int T)
{
    long idx = (long)blockIdx.x * 256 + threadIdx.x;
    int i = idx & 31;
    long r = idx >> 5;
    int h = (int)(r % NHEADS);
    int tok = (int)(r / NHEADS);
    if (tok >= T) return;
    int pos = tok;
    for (int b = 1; b <= B; b++) if (tok >= cu[b]) pos = tok - cu[b];
    float f = (float)pos * exp2f(-(float)i * 0.41524100558003436f);
    float s, c;
    sincosf(f, &s, &c);
    long base = (long)tok * QKV_LD + h * HDIM + i;
    {
        float q1 = __bfloat162float(qkv[base]);
        float q2 = __bfloat162float(qkv[base + 32]);
        qkv[base]      = __float2bfloat16(q1 * c - q2 * s);
        qkv[base + 32] = __float2bfloat16(q2 * c + q1 * s);
    }
    {
        long kb = base + E_DIM;
        float k1 = __bfloat162float(qkv[kb]);
        float k2 = __bfloat162float(qkv[kb + 32]);
        qkv[kb]      = __float2bfloat16(k1 * c - k2 * s);
        qkv[kb + 32] = __float2bfloat16(k2 * c + k1 * s);
    }
}

// ---------------- flash attention: round-6 = occupancy + short chains ----------------
// Round-5 post-mortem: all pipes <55%, occupancy 17% (80 KB LDS -> 2 blocks/CU),
// total pipe work ~35us of a 120us kernel => LATENCY-bound, not pipe-bound. T15
// overlap didn't help (reverted). This round: KVBLK=64, K/V double-buffered ->
// LDS 32 KB -> 4 blocks/CU (launch_bounds(256,4), VGPR cap 128; S halves to 32
// floats). Tree reductions cut the serial fmax chain 32->4 deep and the ls-sum
// chain 64->6 deep. Keeps: 2-phase staging, XOR swizzles, setprio, defer-max,
// cvt_pk pack. S^T = K.Q^T; P^T feeds O^T = V^T.P^T from registers.
__global__ __launch_bounds__(256, 4) void attn_kernel(
    const __hip_bfloat16* __restrict__ qkv, const __hip_bfloat16* __restrict__ vt,
    const int* __restrict__ cu, __hip_bfloat16* __restrict__ obuf, int B, int T)
{
    __shared__ __align__(16) __hip_bfloat16 Ks[2][64 * 64];  // [key][d] swizzled, 2x8 KB
    __shared__ __align__(16) __hip_bfloat16 Vs[2][64 * 64];  // [d][key] swizzled, 2x8 KB

    int idx = blockIdx.x;
    int h = idx % NHEADS;
    int gt = idx / NHEADS;
    int b = 0, l = 0, seq0 = 0;
    for (; b < B; ++b) {
        seq0 = cu[b];
        l = cu[b + 1] - seq0;
        int ntile = (l + 127) >> 7;
        if (gt < ntile) break;
        gt -= ntile;
    }
    if (b == B) return;
    int q0 = gt * 128;
    const int NT = (l + 63) >> 6;

    const int t = threadIdx.x;
    const int wv = t >> 6, ln = t & 63;
    const int m16 = ln & 15, q4 = ln >> 4;

    // K: slot s2 -> key s2>>3, chunk (s2&7)^(key&7); V: d s2>>3, chunk (s2&7)^(d&7)
    auto stage_full = [&](int kv0n, int bi) {
        #pragma unroll
        for (int i = 0; i < 2; i++) {
            int s2 = i * 256 + t;
            int key = s2 >> 3, cg = (s2 & 7) ^ (key & 7);
            gl_lds16(qkv + (long)(seq0 + kv0n + key) * QKV_LD + E_DIM + h * HDIM + cg * 8,
                     (char*)&Ks[bi][0] + (size_t)(i * 256 + wv * 64) * 16);
        }
        #pragma unroll
        for (int i = 0; i < 2; i++) {
            int s2 = i * 256 + t;
            int d = s2 >> 3, cg = (s2 & 7) ^ (d & 7);
            gl_lds16(vt + (long)(h * HDIM + d) * T + seq0 + kv0n + cg * 8,
                     (char*)&Vs[bi][0] + (size_t)(i * 256 + wv * 64) * 16);
        }
    };
    auto stage_tail = [&](int kv0n, int bi) {   // dead in this workload (l % 128 == 0)
        #pragma unroll
        for (int i = 0; i < 2; i++) {
            int s2 = i * 256 + t;
            int key = s2 >> 3, c = s2 & 7;
            bf8_t v = (bf8_t)0;
            if (kv0n + key < l)
                v = *(const bf8_t*)(qkv + (long)(seq0 + kv0n + key) * QKV_LD + E_DIM + h * HDIM + c * 8);
            *(bf8_t*)&Ks[bi][key * 64 + (c ^ (key & 7)) * 8] = v;
        }
        #pragma unroll
        for (int i = 0; i < 2; i++) {
            int s2 = i * 256 + t;
            int d = s2 >> 3, c = s2 & 7;
            bf8_t v = (bf8_t)0;
            int tb = kv0n + c * 8;
            #pragma unroll
            for (int u = 0; u < 8; u++)
                if (tb + u < l)
                    v[u] = *(const short*)&vt[(long)(h * HDIM + d) * T + seq0 + tb + u];
            *(bf8_t*)&Vs[bi][d * 64 + (c ^ (d & 7)) * 8] = v;
        }
    };

    // prologue: issue staging of tile 0 first, then load Q while it flies
    if (64 <= l) stage_full(0, 0); else stage_tail(0, 0);

    // Q B-frags in registers: bq[nt][kc] = B[k=kc*32+q4*8+j][n=m16]
    bf8_t bq[2][2];
    #pragma unroll
    for (int nt = 0; nt < 2; nt++) {
        int qrow = q0 + wv * 32 + nt * 16 + m16;
        #pragma unroll
        for (int kc = 0; kc < 2; kc++) {
            bf8_t v = (bf8_t)0;
            if (qrow < l)
                v = *(const bf8_t*)(qkv + (long)(seq0 + qrow) * QKV_LD + h * HDIM + kc * 32 + q4 * 8);
            bq[nt][kc] = v;
        }
    }

    f4_t oacc[2][4] = {};
    float m_s[2] = {-1e30f, -1e30f};
    float l_s[2] = {0.0f, 0.0f};

    const int ksw0 = (q4 ^ (m16 & 7)) * 8;        // slot of global chunk q4
    const int ksw1 = ((4 + q4) ^ (m16 & 7)) * 8;  // slot of global chunk 4+q4

    asm volatile("s_waitcnt vmcnt(0) lgkmcnt(0)" ::: "memory");
    __builtin_amdgcn_s_barrier();

    for (int it = 0; it < NT; ++it) {
        const int kv0 = it << 6;
        const bool full = (kv0 + 64 <= l);
        if (it + 1 < NT) {                       // issue next tile's loads NOW
            int kvn = kv0 + 64;
            if (kvn + 64 <= l) stage_full(kvn, (it + 1) & 1);
            else stage_tail(kvn, (it + 1) & 1);
        }
        const __hip_bfloat16* Kb = Ks[it & 1];
        const __hip_bfloat16* Vb = Vs[it & 1];

        // S^T = K.Q^T : S[nt][mt] holds S^T[key=mt*16+q4*4+r][qrow=m16]
        f4_t S[2][4];
        __builtin_amdgcn_s_setprio(1);
        #pragma unroll
        for (int mt = 0; mt < 4; mt++) {
            const __hip_bfloat16* krow = &Kb[(mt * 16 + m16) * 64];
            bf8_t ak0 = *(const bf8_t*)(krow + ksw0);
            bf8_t ak1 = *(const bf8_t*)(krow + ksw1);
            #pragma unroll
            for (int nt = 0; nt < 2; nt++) {
                f4_t a = {};
                a = mfma16x32(ak0, bq[nt][0], a);
                a = mfma16x32(ak1, bq[nt][1], a);
                S[nt][mt] = a;
            }
        }
        __builtin_amdgcn_s_setprio(0);

        if (!full) {
            #pragma unroll
            for (int mt = 0; mt < 4; mt++) {
                #pragma unroll
                for (int r = 0; r < 4; r++) {
                    bool valid = (kv0 + mt * 16 + q4 * 4 + r) < l;
                    #pragma unroll
                    for (int nt = 0; nt < 2; nt++)
                        if (!valid) S[nt][mt][r] = -1e30f;
                }
            }
        }

        // online softmax (base-2 domain; log2e folded into Wq/bq) + defer-max (THR=8)
        // tree reductions: fmax depth 4 (was a 32-chain), ls partials depth ~6 (was 64)
        #pragma unroll
        for (int nt = 0; nt < 2; nt++) {
            float pm[4];
            #pragma unroll
            for (int mt = 0; mt < 4; mt++)
                pm[mt] = fmaxf(fmaxf(S[nt][mt][0], S[nt][mt][1]),
                               fmaxf(S[nt][mt][2], S[nt][mt][3]));
            float mx = fmaxf(fmaxf(pm[0], pm[1]), fmaxf(pm[2], pm[3]));
            mx = fmaxf(mx, __shfl_xor(mx, 16));
            mx = fmaxf(mx, __shfl_xor(mx, 32));
            if (!__all(mx - m_s[nt] <= 8.0f)) {
                float mn = fmaxf(m_s[nt], mx);
                float al = exp2f(m_s[nt] - mn);
                m_s[nt] = mn;
                l_s[nt] *= al;
                #pragma unroll
                for (int dt = 0; dt < 4; dt++)
                    #pragma unroll
                    for (int r = 0; r < 4; r++)
                        oacc[nt][dt][r] *= al;
            }
            float mcur = m_s[nt];
            float ps[4];
            #pragma unroll
            for (int mt = 0; mt < 4; mt++) {
                f4_t p;
                p[0] = exp2f(S[nt][mt][0] - mcur);
                p[1] = exp2f(S[nt][mt][1] - mcur);
                p[2] = exp2f(S[nt][mt][2] - mcur);
                p[3] = exp2f(S[nt][mt][3] - mcur);
                S[nt][mt] = p;
                ps[mt] = (p[0] + p[1]) + (p[2] + p[3]);
            }
            l_s[nt] += (ps[0] + ps[1]) + (ps[2] + ps[3]);
        }

        // O^T += V^T . P^T  (A=V^T from swizzled LDS, B=P^T packed in-place)
        __builtin_amdgcn_s_setprio(1);
        #pragma unroll
        for (int mt = 0; mt < 4; mt++) {
            bf4_t bp0 = pk4(S[0][mt]);
            bf4_t bp1 = pk4(S[1][mt]);
            const int vsw = ((mt * 2 + (q4 >> 1)) ^ (m16 & 7)) * 8 + (q4 & 1) * 4;
            #pragma unroll
            for (int dt = 0; dt < 4; dt++) {
                bf4_t av = *(const bf4_t*)&Vb[(dt * 16 + m16) * 64 + vsw];
                oacc[0][dt] = mfma16x16(av, bp0, oacc[0][dt]);
                oacc[1][dt] = mfma16x16(av, bp1, oacc[1][dt]);
            }
        }
        __builtin_amdgcn_s_setprio(0);

        if (it + 1 < NT) {
            // wait for next tile's staging (issued before compute -> mostly landed)
            // and make all waves' LDS writes visible; ONE barrier per tile.
            asm volatile("s_waitcnt vmcnt(0) lgkmcnt(0)" ::: "memory");
            __builtin_amdgcn_s_barrier();
        }
    }

    // finalize
    #pragma unroll
    for (int nt = 0; nt < 2; nt++) {
        float ls = l_s[nt];
        ls += __shfl_xor(ls, 16);
        ls += __shfl_xor(ls, 32);
        float inv = 1.0f / ls;
        int qrow = q0 + wv * 32 + nt * 16 + m16;
        if (qrow < l) {
            #pragma unroll
            for (int dt = 0; dt < 4; dt++) {
                f4_t o;
                #pragma unroll
                for (int r = 0; r < 4; r++)
                    o[r] = oacc[nt][dt][r] * inv;
                *(bf4_t*)&obuf[(long)(seq0 + qrow) * E_DIM + h * HDIM + dt * 16 + q4 * 4] = pk4(o);
            }
        }
    }
}

// ---------------- launch ----------------
extern "C" void kernel_launch(void* const* d_in, const int* in_sizes, int n_in,
                              void* d_out, int out_size, void* d_ws, size_t ws_size,
                              hipStream_t stream) {
    const int E = E_DIM;
    const int T = in_sizes[0] / E;      // 8192
    const int B = in_sizes[1] - 1;      // 8

    const float* x  = (const float*)d_in[0];
    const int*   cu = (const int*)d_in[1];
    const float* Wq = (const float*)d_in[3];
    const float* bq = (const float*)d_in[4];
    const float* Wk = (const float*)d_in[5];
    const float* bk = (const float*)d_in[6];
    const float* Wv = (const float*)d_in[7];
    const float* bv = (const float*)d_in[8];
    const float* Wo = (const float*)d_in[9];
    const float* bo = (const float*)d_in[10];

    char* ws = (char*)d_ws;
    size_t off = 0;
    auto alloc = [&](size_t bytes) -> void* {
        void* p = ws + off;
        off = (off + bytes + 255) & ~(size_t)255;
        return p;
    };
    __hip_bfloat16* xbf   = (__hip_bfloat16*)alloc((size_t)T * E * 2);
    __hip_bfloat16* wqkv  = (__hip_bfloat16*)alloc((size_t)3 * E * E * 2);
    __hip_bfloat16* wobf  = (__hip_bfloat16*)alloc((size_t)E * E * 2);
    float*          bqkv  = (float*)alloc((size_t)3 * E * 4);
    __hip_bfloat16* qkvb  = (__hip_bfloat16*)alloc((size_t)T * 3 * E * 2);
    __hip_bfloat16* vt    = (__hip_bfloat16*)alloc((size_t)E * T * 2);
    __hip_bfloat16* obuf  = xbf;  // alias: x_bf dead after QKV GEMM

    long nx8 = (long)T * E / 8;
    long nw8 = (long)E * E / 8;
    long nb8 = (long)3 * E / 8;
    long total = nx8 + 4 * nw8 + nb8;
    int pblocks = (int)((total + 255) / 256);
    prep_kernel<<<pblocks, 256, 0, stream>>>(x, Wq, Wk, Wv, Wo, bq, bk, bv,
                                             xbf, wqkv, wobf, bqkv, nx8, nw8, nb8);

    // QKV projection: 256^2-tile pipelined GEMM; V columns written transposed to vt
    gemm256<<<(T / 256) * (3 * E / 256), 512, 0, stream>>>(
        xbf, wqkv, bqkv, qkvb, vt, T, T, 3 * E, E, 3 * E);

    rope_kernel<<<(int)(((long)T * NHEADS * 32) / 256), 256, 0, stream>>>(qkvb, cu, B, T);

    // 128-row q-tiles: upper bound on sum of per-seq ceil(l/128)
    int qtiles_ub = T / 128 + B;
    attn_kernel<<<qtiles_ub * NHEADS, 256, 0, stream>>>(qkvb, vt, cu, obuf, B, T);

    // output projection: N=1280 -> only 160 blocks at 256^2; keep 128^2 (640 blocks)
    gemm_nt<false><<<dim3(E / 128, T / 128), 256, 0, stream>>>(
        obuf, wobf, bo, d_out, T, E, E, E);
}

// Round 7
// 380.682 us; speedup vs baseline: 1.3407x; 1.0097x over previous
//
#include <hip/hip_runtime.h>
#include <hip/hip_bf16.h>
#include <cstdint>

#define E_DIM   1280
#define NHEADS  20
#define HDIM    64
#define QKV_LD  3840   // 3*E

typedef __attribute__((ext_vector_type(8))) short bf8_t;   // 8 bf16 (4 VGPRs)
typedef __attribute__((ext_vector_type(4))) short bf4_t;   // 4 bf16 (2 VGPRs)
typedef __attribute__((ext_vector_type(4))) float f4_t;    // MFMA accumulator

__device__ __forceinline__ short f2bs(float f) {
    union { __hip_bfloat16 h; short s; } u;
    u.h = __float2bfloat16(f);
    return u.s;
}

// hardware packed f32x2 -> bf16x2 (RNE), T12 recipe: no builtin on gfx950
__device__ __forceinline__ bf4_t pk4(f4_t s) {
    union { bf4_t v; uint32_t u[2]; } r;
    asm("v_cvt_pk_bf16_f32 %0, %1, %2" : "=v"(r.u[0]) : "v"(s[0]), "v"(s[1]));
    asm("v_cvt_pk_bf16_f32 %0, %1, %2" : "=v"(r.u[1]) : "v"(s[2]), "v"(s[3]));
    return r.v;
}

__device__ __forceinline__ f4_t mfma16x32(bf8_t a, bf8_t b, f4_t c) {
    return __builtin_amdgcn_mfma_f32_16x16x32_bf16(a, b, c, 0, 0, 0);
}
__device__ __forceinline__ f4_t mfma16x16(bf4_t a, bf4_t b, f4_t c) {
    return __builtin_amdgcn_mfma_f32_16x16x16bf16_1k(a, b, c, 0, 0, 0);
}

// async global->LDS, 16B per lane. LDS dest is wave-uniform base + lane*16.
__device__ __forceinline__ void gl_lds16(const void* g, void* l) {
    auto gp = reinterpret_cast<__attribute__((address_space(1))) unsigned int*>(
        reinterpret_cast<uintptr_t>(g));
    auto lp = reinterpret_cast<__attribute__((address_space(3))) unsigned int*>(
        reinterpret_cast<uintptr_t>(l));
    __builtin_amdgcn_global_load_lds(gp, lp, 16, 0, 0);
}

// ---------------- prep: casts + weight concat + bias concat ----------------
// Wq/bq scale = d^-0.5 * log2(e): softmax computed in base-2 domain (exp2f).
#define QSCALE 0.18033688011112042f

__device__ __forceinline__ void cvt8(__hip_bfloat16* dst, const float* src, float sc) {
    float4 a = *(const float4*)src;
    float4 b = *(const float4*)(src + 4);
    bf8_t v;
    v[0] = f2bs(a.x * sc); v[1] = f2bs(a.y * sc); v[2] = f2bs(a.z * sc); v[3] = f2bs(a.w * sc);
    v[4] = f2bs(b.x * sc); v[5] = f2bs(b.y * sc); v[6] = f2bs(b.z * sc); v[7] = f2bs(b.w * sc);
    *(bf8_t*)dst = v;
}

__global__ __launch_bounds__(256) void prep_kernel(
    const float* __restrict__ x,
    const float* __restrict__ wq, const float* __restrict__ wk,
    const float* __restrict__ wv, const float* __restrict__ wo,
    const float* __restrict__ bq, const float* __restrict__ bk, const float* __restrict__ bv,
    __hip_bfloat16* __restrict__ xbf, __hip_bfloat16* __restrict__ wqkv,
    __hip_bfloat16* __restrict__ wobf, float* __restrict__ bqkv,
    long nx8, long nw8, long nb8)
{
    long u = (long)blockIdx.x * 256 + threadIdx.x;
    if (u < nx8) { cvt8(xbf + u * 8, x + u * 8, 1.0f); return; }
    u -= nx8;
    if (u < 3 * nw8) {
        long e = u * 8;
        long w1 = nw8 * 8;
        const float* src; float sc;
        if (e < w1)            { src = wq + e;           sc = QSCALE; }
        else if (e < 2 * w1)   { src = wk + (e - w1);    sc = 1.0f; }
        else                   { src = wv + (e - 2*w1);  sc = 1.0f; }
        cvt8(wqkv + e, src, sc);
        return;
    }
    u -= 3 * nw8;
    if (u < nw8) { cvt8(wobf + u * 8, wo + u * 8, 1.0f); return; }
    u -= nw8;
    if (u < nb8) {
        long e = u * 8;
        #pragma unroll
        for (int j = 0; j < 8; j++) {
            long i = e + j;
            float v;
            if (i < E_DIM)           v = bq[i] * QSCALE;
            else if (i < 2 * E_DIM)  v = bk[i - E_DIM];
            else                     v = bv[i - 2 * E_DIM];
            bqkv[i] = v;
        }
    }
}

// ---------------- m97-style NT GEMM (output proj): C = A*B^T + bias ----------------
template<bool BF16_OUT>
__global__ __launch_bounds__(256, 3) void gemm_nt(
    const __hip_bfloat16* __restrict__ A, const __hip_bfloat16* __restrict__ Bw,
    const float* __restrict__ bias, void* __restrict__ Cout,
    int M, int N, int K, int ldc)
{
    __shared__ __align__(16) __hip_bfloat16 As[128 * 32];
    __shared__ __align__(16) __hip_bfloat16 Bs[128 * 32];
    const int t = threadIdx.x;
    const int wv = t >> 6;
    const int ln = t & 63;
    const int m16 = ln & 15, q4 = ln >> 4;
    const int row0 = blockIdx.y * 128, col0 = blockIdx.x * 128;
    const int wm = (wv >> 1) * 64, wn = (wv & 1) * 64;

    f4_t acc[4][4] = {};

    for (int k0 = 0; k0 < K; k0 += 32) {
        #pragma unroll
        for (int i = 0; i < 2; i++) {
            int s = i * 256 + t;
            int r = s >> 2, c = s & 3;
            gl_lds16(A + (size_t)(row0 + r) * K + k0 + c * 8,
                     As + (size_t)(i * 256 + wv * 64) * 8);
        }
        #pragma unroll
        for (int i = 0; i < 2; i++) {
            int s = i * 256 + t;
            int r = s >> 2, c = s & 3;
            gl_lds16(Bw + (size_t)(col0 + r) * K + k0 + c * 8,
                     Bs + (size_t)(i * 256 + wv * 64) * 8);
        }
        __syncthreads();
        bf8_t af[4], bfr[4];
        #pragma unroll
        for (int mt = 0; mt < 4; mt++)
            af[mt] = *(const bf8_t*)&As[(wm + mt * 16 + m16) * 32 + q4 * 8];
        #pragma unroll
        for (int nt = 0; nt < 4; nt++)
            bfr[nt] = *(const bf8_t*)&Bs[(wn + nt * 16 + m16) * 32 + q4 * 8];
        #pragma unroll
        for (int mt = 0; mt < 4; mt++)
            #pragma unroll
            for (int nt = 0; nt < 4; nt++)
                acc[mt][nt] = mfma16x32(af[mt], bfr[nt], acc[mt][nt]);
        __syncthreads();
    }

    #pragma unroll
    for (int nt = 0; nt < 4; nt++) {
        int cg = col0 + wn + nt * 16 + m16;
        float bv = bias[cg];
        #pragma unroll
        for (int mt = 0; mt < 4; mt++) {
            #pragma unroll
            for (int r = 0; r < 4; r++) {
                int rg = row0 + wm + mt * 16 + q4 * 4 + r;
                float v = acc[mt][nt][r] + bv;
                if constexpr (BF16_OUT)
                    ((__hip_bfloat16*)Cout)[(long)rg * ldc + cg] = __float2bfloat16(v);
                else
                    ((float*)Cout)[(long)rg * ldc + cg] = v;
            }
        }
    }
}

// ---------------- 256x256 pipelined NT GEMM for QKV (T1+T2+T3/T4+T5 stack) --------
// V-column blocks (col0 >= 2E, block-uniform) write TRANSPOSED to vt[(cg-2E)*T + rg]
// as 8B bf4 stores (4 consecutive r = 4 consecutive tokens) -> vtrans_kernel deleted.
__global__ __launch_bounds__(512, 2) void gemm256(
    const __hip_bfloat16* __restrict__ A, const __hip_bfloat16* __restrict__ Bw,
    const float* __restrict__ bias, __hip_bfloat16* __restrict__ Cout,
    __hip_bfloat16* __restrict__ vtout, int Tdim,
    int M, int N, int K, int ldc)
{
    __shared__ __align__(16) __hip_bfloat16 As[2][256 * 64];  // 2 x 32 KB
    __shared__ __align__(16) __hip_bfloat16 Bs[2][256 * 64];  // 2 x 32 KB

    const int t = threadIdx.x;
    const int wv = t >> 6, ln = t & 63;
    const int m16 = ln & 15, q4 = ln >> 4;
    const int wr = wv >> 2, wc = wv & 3;   // 2 x 4 wave grid

    const int gx = N >> 8;
    const int nwg = gridDim.x;
    const int id = blockIdx.x;
    const int swz = ((nwg & 7) == 0) ? (id & 7) * (nwg >> 3) + (id >> 3) : id;  // T1 (bijective: nwg%8==0)
    const int col0 = (swz % gx) << 8;
    const int row0 = (swz / gx) << 8;

    const int NT = K >> 6;   // K-tiles of 64

    // stage one 256x64 tile: linear LDS dest (slot order), inverse-swizzled global src
    auto stage = [&](const __hip_bfloat16* src, __hip_bfloat16* dst) {
        #pragma unroll
        for (int i = 0; i < 4; i++) {
            int s = i * 512 + t;
            int r = s >> 3, c = (s & 7) ^ (r & 7);
            gl_lds16(src + (size_t)r * K + c * 8,
                     (char*)dst + (size_t)(i * 512 + wv * 64) * 16);
        }
    };

    // prologue: tiles 0 and 1
    stage(A  + (size_t)row0 * K,      &As[0][0]);
    stage(Bw + (size_t)col0 * K,      &Bs[0][0]);
    if (NT > 1) {
        stage(A  + (size_t)row0 * K + 64, &As[1][0]);
        stage(Bw + (size_t)col0 * K + 64, &Bs[1][0]);
        asm volatile("s_waitcnt vmcnt(8)" ::: "memory");   // tile 0 landed; tile 1 in flight
    } else {
        asm volatile("s_waitcnt vmcnt(0)" ::: "memory");
    }
    __builtin_amdgcn_s_barrier();

    f4_t acc[8][4] = {};

    for (int kt = 0; kt < NT; kt++) {
        const __hip_bfloat16* Ab = &As[kt & 1][0];
        const __hip_bfloat16* Bb = &Bs[kt & 1][0];

        auto lda = [&](const __hip_bfloat16* base, int r, int kc) {
            return *(const bf8_t*)&base[r * 64 + ((((kc << 2) | q4) ^ (r & 7)) << 3)];
        };

        bf8_t afr[4][2], bf0[2][2], bf1[2][2];
        // Q(mh0,nh0): af half 0 (8 reads) + bf half 0 (4 reads)
        #pragma unroll
        for (int mt = 0; mt < 4; mt++)
            #pragma unroll
            for (int kc = 0; kc < 2; kc++)
                afr[mt][kc] = lda(Ab, wr * 128 + mt * 16 + m16, kc);
        #pragma unroll
        for (int nt = 0; nt < 2; nt++)
            #pragma unroll
            for (int kc = 0; kc < 2; kc++)
                bf0[nt][kc] = lda(Bb, wc * 64 + nt * 16 + m16, kc);

        __builtin_amdgcn_s_setprio(1);
        #pragma unroll
        for (int mt = 0; mt < 4; mt++)
            #pragma unroll
            for (int nt = 0; nt < 2; nt++)
                #pragma unroll
                for (int kc = 0; kc < 2; kc++)
                    acc[mt][nt] = mfma16x32(afr[mt][kc], bf0[nt][kc], acc[mt][nt]);
        __builtin_amdgcn_s_setprio(0);

        // Q(mh0,nh1): new bf half 1 (4 reads)
        #pragma unroll
        for (int nt = 0; nt < 2; nt++)
            #pragma unroll
            for (int kc = 0; kc < 2; kc++)
                bf1[nt][kc] = lda(Bb, wc * 64 + (2 + nt) * 16 + m16, kc);

        __builtin_amdgcn_s_setprio(1);
        #pragma unroll
        for (int mt = 0; mt < 4; mt++)
            #pragma unroll
            for (int nt = 0; nt < 2; nt++)
                #pragma unroll
                for (int kc = 0; kc < 2; kc++)
                    acc[mt][2 + nt] = mfma16x32(afr[mt][kc], bf1[nt][kc], acc[mt][2 + nt]);
        __builtin_amdgcn_s_setprio(0);

        // Q(mh1,nh1): new af half 1 (8 reads)
        #pragma unroll
        for (int mt = 0; mt < 4; mt++)
            #pragma unroll
            for (int kc = 0; kc < 2; kc++)
                afr[mt][kc] = lda(Ab, wr * 128 + (4 + mt) * 16 + m16, kc);

        __builtin_amdgcn_s_setprio(1);
        #pragma unroll
        for (int mt = 0; mt < 4; mt++)
            #pragma unroll
            for (int nt = 0; nt < 2; nt++)
                #pragma unroll
                for (int kc = 0; kc < 2; kc++)
                    acc[4 + mt][2 + nt] = mfma16x32(afr[mt][kc], bf1[nt][kc], acc[4 + mt][2 + nt]);
        __builtin_amdgcn_s_setprio(0);

        // Q(mh1,nh0): bf half 0 still live
        __builtin_amdgcn_s_setprio(1);
        #pragma unroll
        for (int mt = 0; mt < 4; mt++)
            #pragma unroll
            for (int nt = 0; nt < 2; nt++)
                #pragma unroll
                for (int kc = 0; kc < 2; kc++)
                    acc[4 + mt][nt] = mfma16x32(afr[mt][kc], bf0[nt][kc], acc[4 + mt][nt]);
        __builtin_amdgcn_s_setprio(0);

        // all reads of slot kt&1 done (per-wave lgkmcnt before MFMA; barrier -> all waves)
        asm volatile("s_waitcnt lgkmcnt(0)" ::: "memory");
        __builtin_amdgcn_s_barrier();

        if (kt + 2 < NT) {   // restage the just-freed slot for tile kt+2
            stage(A  + (size_t)row0 * K + (size_t)(kt + 2) * 64, &As[kt & 1][0]);
            stage(Bw + (size_t)col0 * K + (size_t)(kt + 2) * 64, &Bs[kt & 1][0]);
        }
        if (kt + 1 < NT) {
            if (kt + 2 < NT)
                asm volatile("s_waitcnt vmcnt(8)" ::: "memory");  // tile kt+1 landed; kt+2 in flight
            else
                asm volatile("s_waitcnt vmcnt(0)" ::: "memory");  // drain last tile
            __builtin_amdgcn_s_barrier();
        }
    }

    if (col0 >= 2 * E_DIM) {
        // V block: write transposed into vt, 8B bf4 per (mt,nt) (4 consecutive tokens)
        #pragma unroll
        for (int nt = 0; nt < 4; nt++) {
            int cg = col0 + wc * 64 + nt * 16 + m16;
            float bval = bias[cg];
            int vrow = cg - 2 * E_DIM;
            #pragma unroll
            for (int mt = 0; mt < 8; mt++) {
                int rg0 = row0 + wr * 128 + mt * 16 + q4 * 4;
                f4_t vv;
                #pragma unroll
                for (int r = 0; r < 4; r++) vv[r] = acc[mt][nt][r] + bval;
                *(bf4_t*)&vtout[(long)vrow * Tdim + rg0] = pk4(vv);
            }
        }
    } else {
        #pragma unroll
        for (int nt = 0; nt < 4; nt++) {
            int cg = col0 + wc * 64 + nt * 16 + m16;
            float bval = bias[cg];
            #pragma unroll
            for (int mt = 0; mt < 8; mt++) {
                #pragma unroll
                for (int r = 0; r < 4; r++) {
                    int rg = row0 + wr * 128 + mt * 16 + q4 * 4 + r;
                    Cout[(long)rg * ldc + cg] = __float2bfloat16(acc[mt][nt][r] + bval);
                }
            }
        }
    }
}

// ---------------- RoPE (in place on q,k sections of qkv) ----------------
__global__ __launch_bounds__(256) void rope_kernel(
    __hip_bfloat16* __restrict__ qkv, const int* __restrict__ cu, int B, int T)
{
    long idx = (long)blockIdx.x * 256 + threadIdx.x;
    int i = idx & 31;
    long r = idx >> 5;
    int h = (int)(r % NHEADS);
    int tok = (int)(r / NHEADS);
    if (tok >= T) return;
    int pos = tok;
    for (int b = 1; b <= B; b++) if (tok >= cu[b]) pos = tok - cu[b];
    float f = (float)pos * exp2f(-(float)i * 0.41524100558003436f);
    float s, c;
    sincosf(f, &s, &c);
    long base = (long)tok * QKV_LD + h * HDIM + i;
    {
        float q1 = __bfloat162float(qkv[base]);
        float q2 = __bfloat162float(qkv[base + 32]);
        qkv[base]      = __float2bfloat16(q1 * c - q2 * s);
        qkv[base + 32] = __float2bfloat16(q2 * c + q1 * s);
    }
    {
        long kb = base + E_DIM;
        float k1 = __bfloat162float(qkv[kb]);
        float k2 = __bfloat162float(qkv[kb + 32]);
        qkv[kb]      = __float2bfloat16(k1 * c - k2 * s);
        qkv[kb + 32] = __float2bfloat16(k2 * c + k1 * s);
    }
}

// ---------------- flash attention: round-7 = round-5 (known-good) + longest-first ----
// Round-6 FAILED (NaN) with 3 simultaneous changes; isolation: this round is the
// byte-identical round-5 kernel (passed, 117.5us) plus ONLY the reverse sequence
// scan (pure bijective blockIdx remap, correctness-neutral). Sequences are sorted
// ascending in cu; scanning in reverse puts 1280-len blocks (NT=20) first, so the
// backfill tail consists of 512-len blocks (NT=8) instead of the longest ones.
// If this passes, the NaN was in {launch_bounds(256,5), pk-f32/max3h} — retest one.
__global__ __launch_bounds__(256, 4) void attn_kernel(
    const __hip_bfloat16* __restrict__ qkv, const __hip_bfloat16* __restrict__ vt,
    const int* __restrict__ cu, __hip_bfloat16* __restrict__ obuf, int B, int T)
{
    __shared__ __align__(16) __hip_bfloat16 Ks[2][64 * 64];  // [key][d] swizzled, 2x8 KB
    __shared__ __align__(16) __hip_bfloat16 Vs[2][64 * 64];  // [d][key] swizzled, 2x8 KB

    int idx = blockIdx.x;
    int h = idx % NHEADS;
    int gt = idx / NHEADS;
    // longest-first: sequences sorted ascending in cu -> scan in REVERSE
    int b = B - 1, l = 0, seq0 = 0;
    for (; b >= 0; --b) {
        seq0 = cu[b];
        l = cu[b + 1] - seq0;
        int ntile = (l + 127) >> 7;
        if (gt < ntile) break;
        gt -= ntile;
    }
    if (b < 0) return;
    int q0 = gt * 128;
    const int NT = (l + 63) >> 6;

    const int t = threadIdx.x;
    const int wv = t >> 6, ln = t & 63;
    const int m16 = ln & 15, q4 = ln >> 4;

    // K: slot s2 -> key s2>>3, chunk (s2&7)^(key&7); V: d s2>>3, chunk (s2&7)^(d&7)
    auto stage_full = [&](int kv0n, int bi) {
        #pragma unroll
        for (int i = 0; i < 2; i++) {
            int s2 = i * 256 + t;
            int key = s2 >> 3, cg = (s2 & 7) ^ (key & 7);
            gl_lds16(qkv + (long)(seq0 + kv0n + key) * QKV_LD + E_DIM + h * HDIM + cg * 8,
                     (char*)&Ks[bi][0] + (size_t)(i * 256 + wv * 64) * 16);
        }
        #pragma unroll
        for (int i = 0; i < 2; i++) {
            int s2 = i * 256 + t;
            int d = s2 >> 3, cg = (s2 & 7) ^ (d & 7);
            gl_lds16(vt + (long)(h * HDIM + d) * T + seq0 + kv0n + cg * 8,
                     (char*)&Vs[bi][0] + (size_t)(i * 256 + wv * 64) * 16);
        }
    };
    auto stage_tail = [&](int kv0n, int bi) {   // dead in this workload (l % 128 == 0)
        #pragma unroll
        for (int i = 0; i < 2; i++) {
            int s2 = i * 256 + t;
            int key = s2 >> 3, c = s2 & 7;
            bf8_t v = (bf8_t)0;
            if (kv0n + key < l)
                v = *(const bf8_t*)(qkv + (long)(seq0 + kv0n + key) * QKV_LD + E_DIM + h * HDIM + c * 8);
            *(bf8_t*)&Ks[bi][key * 64 + (c ^ (key & 7)) * 8] = v;
        }
        #pragma unroll
        for (int i = 0; i < 2; i++) {
            int s2 = i * 256 + t;
            int d = s2 >> 3, c = s2 & 7;
            bf8_t v = (bf8_t)0;
            int tb = kv0n + c * 8;
            #pragma unroll
            for (int u = 0; u < 8; u++)
                if (tb + u < l)
                    v[u] = *(const short*)&vt[(long)(h * HDIM + d) * T + seq0 + tb + u];
            *(bf8_t*)&Vs[bi][d * 64 + (c ^ (d & 7)) * 8] = v;
        }
    };

    // prologue: issue staging of tile 0 first, then load Q while it flies
    if (64 <= l) stage_full(0, 0); else stage_tail(0, 0);

    // Q B-frags in registers: bq[nt][kc] = B[k=kc*32+q4*8+j][n=m16]
    bf8_t bq[2][2];
    #pragma unroll
    for (int nt = 0; nt < 2; nt++) {
        int qrow = q0 + wv * 32 + nt * 16 + m16;
        #pragma unroll
        for (int kc = 0; kc < 2; kc++) {
            bf8_t v = (bf8_t)0;
            if (qrow < l)
                v = *(const bf8_t*)(qkv + (long)(seq0 + qrow) * QKV_LD + h * HDIM + kc * 32 + q4 * 8);
            bq[nt][kc] = v;
        }
    }

    f4_t oacc[2][4] = {};
    float m_s[2] = {-1e30f, -1e30f};
    float l_s[2] = {0.0f, 0.0f};

    const int ksw0 = (q4 ^ (m16 & 7)) * 8;        // slot of global chunk q4
    const int ksw1 = ((4 + q4) ^ (m16 & 7)) * 8;  // slot of global chunk 4+q4

    asm volatile("s_waitcnt vmcnt(0) lgkmcnt(0)" ::: "memory");
    __builtin_amdgcn_s_barrier();

    for (int it = 0; it < NT; ++it) {
        const int kv0 = it << 6;
        const bool full = (kv0 + 64 <= l);
        if (it + 1 < NT) {                       // issue next tile's loads NOW
            int kvn = kv0 + 64;
            if (kvn + 64 <= l) stage_full(kvn, (it + 1) & 1);
            else stage_tail(kvn, (it + 1) & 1);
        }
        const __hip_bfloat16* Kb = Ks[it & 1];
        const __hip_bfloat16* Vb = Vs[it & 1];

        // S^T = K.Q^T : S[nt][mt] holds S^T[key=mt*16+q4*4+r][qrow=m16]
        f4_t S[2][4];
        __builtin_amdgcn_s_setprio(1);
        #pragma unroll
        for (int mt = 0; mt < 4; mt++) {
            const __hip_bfloat16* krow = &Kb[(mt * 16 + m16) * 64];
            bf8_t ak0 = *(const bf8_t*)(krow + ksw0);
            bf8_t ak1 = *(const bf8_t*)(krow + ksw1);
            #pragma unroll
            for (int nt = 0; nt < 2; nt++) {
                f4_t a = {};
                a = mfma16x32(ak0, bq[nt][0], a);
                a = mfma16x32(ak1, bq[nt][1], a);
                S[nt][mt] = a;
            }
        }
        __builtin_amdgcn_s_setprio(0);

        if (!full) {
            #pragma unroll
            for (int mt = 0; mt < 4; mt++) {
                #pragma unroll
                for (int r = 0; r < 4; r++) {
                    bool valid = (kv0 + mt * 16 + q4 * 4 + r) < l;
                    #pragma unroll
                    for (int nt = 0; nt < 2; nt++)
                        if (!valid) S[nt][mt][r] = -1e30f;
                }
            }
        }

        // online softmax (base-2 domain; log2e folded into Wq/bq) + defer-max (THR=8)
        // tree reductions: fmax depth 4 (was a 32-chain), ls partials depth ~6 (was 64)
        #pragma unroll
        for (int nt = 0; nt < 2; nt++) {
            float pm[4];
            #pragma unroll
            for (int mt = 0; mt < 4; mt++)
                pm[mt] = fmaxf(fmaxf(S[nt][mt][0], S[nt][mt][1]),
                               fmaxf(S[nt][mt][2], S[nt][mt][3]));
            float mx = fmaxf(fmaxf(pm[0], pm[1]), fmaxf(pm[2], pm[3]));
            mx = fmaxf(mx, __shfl_xor(mx, 16));
            mx = fmaxf(mx, __shfl_xor(mx, 32));
            if (!__all(mx - m_s[nt] <= 8.0f)) {
                float mn = fmaxf(m_s[nt], mx);
                float al = exp2f(m_s[nt] - mn);
                m_s[nt] = mn;
                l_s[nt] *= al;
                #pragma unroll
                for (int dt = 0; dt < 4; dt++)
                    #pragma unroll
                    for (int r = 0; r < 4; r++)
                        oacc[nt][dt][r] *= al;
            }
            float mcur = m_s[nt];
            float ps[4];
            #pragma unroll
            for (int mt = 0; mt < 4; mt++) {
                f4_t p;
                p[0] = exp2f(S[nt][mt][0] - mcur);
                p[1] = exp2f(S[nt][mt][1] - mcur);
                p[2] = exp2f(S[nt][mt][2] - mcur);
                p[3] = exp2f(S[nt][mt][3] - mcur);
                S[nt][mt] = p;
                ps[mt] = (p[0] + p[1]) + (p[2] + p[3]);
            }
            l_s[nt] += (ps[0] + ps[1]) + (ps[2] + ps[3]);
        }

        // O^T += V^T . P^T  (A=V^T from swizzled LDS, B=P^T packed in-place)
        __builtin_amdgcn_s_setprio(1);
        #pragma unroll
        for (int mt = 0; mt < 4; mt++) {
            bf4_t bp0 = pk4(S[0][mt]);
            bf4_t bp1 = pk4(S[1][mt]);
            const int vsw = ((mt * 2 + (q4 >> 1)) ^ (m16 & 7)) * 8 + (q4 & 1) * 4;
            #pragma unroll
            for (int dt = 0; dt < 4; dt++) {
                bf4_t av = *(const bf4_t*)&Vb[(dt * 16 + m16) * 64 + vsw];
                oacc[0][dt] = mfma16x16(av, bp0, oacc[0][dt]);
                oacc[1][dt] = mfma16x16(av, bp1, oacc[1][dt]);
            }
        }
        __builtin_amdgcn_s_setprio(0);

        if (it + 1 < NT) {
            // wait for next tile's staging (issued before compute -> mostly landed)
            // and make all waves' LDS writes visible; ONE barrier per tile.
            asm volatile("s_waitcnt vmcnt(0) lgkmcnt(0)" ::: "memory");
            __builtin_amdgcn_s_barrier();
        }
    }

    // finalize
    #pragma unroll
    for (int nt = 0; nt < 2; nt++) {
        float ls = l_s[nt];
        ls += __shfl_xor(ls, 16);
        ls += __shfl_xor(ls, 32);
        float inv = 1.0f / ls;
        int qrow = q0 + wv * 32 + nt * 16 + m16;
        if (qrow < l) {
            #pragma unroll
            for (int dt = 0; dt < 4; dt++) {
                f4_t o;
                #pragma unroll
                for (int r = 0; r < 4; r++)
                    o[r] = oacc[nt][dt][r] * inv;
                *(bf4_t*)&obuf[(long)(seq0 + qrow) * E_DIM + h * HDIM + dt * 16 + q4 * 4] = pk4(o);
            }
        }
    }
}

// ---------------- launch ----------------
extern "C" void kernel_launch(void* const* d_in, const int* in_sizes, int n_in,
                              void* d_out, int out_size, void* d_ws, size_t ws_size,
                              hipStream_t stream) {
    const int E = E_DIM;
    const int T = in_sizes[0] / E;      // 8192
    const int B = in_sizes[1] - 1;      // 8

    const float* x  = (const float*)d_in[0];
    const int*   cu = (const int*)d_in[1];
    const float* Wq = (const float*)d_in[3];
    const float* bq = (const float*)d_in[4];
    const float* Wk = (const float*)d_in[5];
    const float* bk = (const float*)d_in[6];
    const float* Wv = (const float*)d_in[7];
    const float* bv = (const float*)d_in[8];
    const float* Wo = (const float*)d_in[9];
    const float* bo = (const float*)d_in[10];

    char* ws = (char*)d_ws;
    size_t off = 0;
    auto alloc = [&](size_t bytes) -> void* {
        void* p = ws + off;
        off = (off + bytes + 255) & ~(size_t)255;
        return p;
    };
    __hip_bfloat16* xbf   = (__hip_bfloat16*)alloc((size_t)T * E * 2);
    __hip_bfloat16* wqkv  = (__hip_bfloat16*)alloc((size_t)3 * E * E * 2);
    __hip_bfloat16* wobf  = (__hip_bfloat16*)alloc((size_t)E * E * 2);
    float*          bqkv  = (float*)alloc((size_t)3 * E * 4);
    __hip_bfloat16* qkvb  = (__hip_bfloat16*)alloc((size_t)T * 3 * E * 2);
    __hip_bfloat16* vt    = (__hip_bfloat16*)alloc((size_t)E * T * 2);
    __hip_bfloat16* obuf  = xbf;  // alias: x_bf dead after QKV GEMM

    long nx8 = (long)T * E / 8;
    long nw8 = (long)E * E / 8;
    long nb8 = (long)3 * E / 8;
    long total = nx8 + 4 * nw8 + nb8;
    int pblocks = (int)((total + 255) / 256);
    prep_kernel<<<pblocks, 256, 0, stream>>>(x, Wq, Wk, Wv, Wo, bq, bk, bv,
                                             xbf, wqkv, wobf, bqkv, nx8, nw8, nb8);

    // QKV projection: 256^2-tile pipelined GEMM; V columns written transposed to vt
    gemm256<<<(T / 256) * (3 * E / 256), 512, 0, stream>>>(
        xbf, wqkv, bqkv, qkvb, vt, T, T, 3 * E, E, 3 * E);

    rope_kernel<<<(int)(((long)T * NHEADS * 32) / 256), 256, 0, stream>>>(qkvb, cu, B, T);

    // 128-row q-tiles: upper bound on sum of per-seq ceil(l/128)
    int qtiles_ub = T / 128 + B;
    attn_kernel<<<qtiles_ub * NHEADS, 256, 0, stream>>>(qkvb, vt, cu, obuf, B, T);

    // output projection: N=1280 -> only 160 blocks at 256^2; keep 128^2 (640 blocks)
    gemm_nt<false><<<dim3(E / 128, T / 128), 256, 0, stream>>>(
        obuf, wobf, bo, d_out, T, E, E, E);
}